// Round 1
// baseline (1339.363 us; speedup 1.0000x reference)
//
#include <hip/hip_runtime.h>
#include <math.h>

// Problem shape (fixed by setup_inputs): B=4, N=4096 (=64*64), C=768, h=12, d=64
#define B_SZ   4
#define N_SEQ  4096
#define C_DIM  768
#define NH     12
#define HD     64
#define NBH    (B_SZ*NH)
#define SCALE  0.125f

// ---------------- rope sin/cos tables (N_SEQ x 64) ----------------
__global__ void rope_table_k(const int* __restrict__ dH, const int* __restrict__ dW,
                             float* __restrict__ sin_t, float* __restrict__ cos_t) {
    int idx = blockIdx.x * 256 + threadIdx.x;
    if (idx >= N_SEQ * HD) return;
    int n = idx >> 6, j = idx & 63;
    int Wd = dW[0];
    int hh = n / Wd, ww = n % Wd;
    int jj = j & 31;
    float pos = (j < 32) ? (float)hh : (float)ww;
    float freq = powf(10000.0f, -((float)(jj >> 1) / 15.0f));
    float th = pos * freq;
    sin_t[idx] = sinf(th);
    cos_t[idx] = cosf(th);
}

// ---------------- fp32 GEMM: out[M][Nn] = A[M][K] @ Bw[Nn][K]^T + bias, opt elu+1 ----------------
#define BM 128
#define BNT 128
#define BK 8
template<int ACT>
__global__ __launch_bounds__(256)
void gemm_nt(const float* __restrict__ A, const float* __restrict__ Bw,
             const float* __restrict__ bias, float* __restrict__ Cc,
             int M, int Nn, int K) {
    __shared__ float As[BM][BK + 4];   // 12 floats/row: 16B-aligned rows, staggered reads
    __shared__ float Bs[BNT][BK + 4];
    int t = threadIdx.x;
    int tx = t & 15, ty = t >> 4;
    int m0 = blockIdx.y * BM, n0 = blockIdx.x * BNT;
    float acc[8][8] = {};
    for (int k0 = 0; k0 < K; k0 += BK) {
        int r = t >> 1, c = (t & 1) * 4;
        float4 a4 = *(const float4*)&A[(size_t)(m0 + r) * K + k0 + c];
        float4 b4 = *(const float4*)&Bw[(size_t)(n0 + r) * K + k0 + c];
        __syncthreads();
        *(float4*)&As[r][c] = a4;
        *(float4*)&Bs[r][c] = b4;
        __syncthreads();
        #pragma unroll
        for (int kk = 0; kk < BK; ++kk) {
            float a[8], b[8];
            #pragma unroll
            for (int i = 0; i < 8; ++i) a[i] = As[ty + 16 * i][kk];
            #pragma unroll
            for (int j = 0; j < 8; ++j) b[j] = Bs[tx + 16 * j][kk];
            #pragma unroll
            for (int i = 0; i < 8; ++i)
                #pragma unroll
                for (int j = 0; j < 8; ++j)
                    acc[i][j] += a[i] * b[j];
        }
    }
    #pragma unroll
    for (int i = 0; i < 8; ++i) {
        int m = m0 + ty + 16 * i;
        #pragma unroll
        for (int j = 0; j < 8; ++j) {
            int n = n0 + tx + 16 * j;
            float v = acc[i][j] + bias[n];
            if (ACT == 1) v = (v > 0.0f) ? (v + 1.0f) : __expf(v);
            Cc[(size_t)m * Nn + n] = v;
        }
    }
}

// ---------------- column sums (pre-rope K, V) -> partials ----------------
__global__ __launch_bounds__(256)
void colsum_partial(const float* __restrict__ Kb, const float* __restrict__ Vb,
                    float* __restrict__ pk, float* __restrict__ pv) {
    // grid (NBH, 16)
    int bh = blockIdx.x, chunk = blockIdx.y;
    int b = bh / NH, h = bh % NH;
    int w = threadIdx.x >> 6, lane = threadIdx.x & 63;
    size_t base = ((size_t)b * N_SEQ) * C_DIM + (size_t)h * HD + lane;
    int n0 = chunk * 256;
    float sk = 0.f, sv = 0.f;
    for (int it = 0; it < 64; ++it) {
        int n = n0 + w + 4 * it;
        size_t off = base + (size_t)n * C_DIM;
        sk += Kb[off];
        sv += Vb[off];
    }
    __shared__ float red[2][4][64];
    red[0][w][lane] = sk; red[1][w][lane] = sv;
    __syncthreads();
    if (threadIdx.x < 64) {
        float k4 = red[0][0][lane] + red[0][1][lane] + red[0][2][lane] + red[0][3][lane];
        float v4 = red[1][0][lane] + red[1][1][lane] + red[1][2][lane] + red[1][3][lane];
        pk[(bh * 16 + chunk) * 64 + lane] = k4;
        pv[(bh * 16 + chunk) * 64 + lane] = v4;
    }
}

__global__ void colsum_reduce(const float* __restrict__ pk, const float* __restrict__ pv,
                              float* __restrict__ kmean, float* __restrict__ vmean) {
    int bh = blockIdx.x, lane = threadIdx.x;  // 64 threads
    float sk = 0, sv = 0;
    for (int c = 0; c < 16; ++c) {
        sk += pk[(bh * 16 + c) * 64 + lane];
        sv += pv[(bh * 16 + c) * 64 + lane];
    }
    kmean[bh * 64 + lane] = sk * (1.0f / N_SEQ);
    vmean[bh * 64 + lane] = sv * (1.0f / N_SEQ);
}

// ---------------- kv = sum_n rope(k)[n] (x) v[n], partial over N-chunks ----------------
#define KVROWS 512
__global__ __launch_bounds__(256)
void kv_partial(const float* __restrict__ Kb, const float* __restrict__ Vb,
                const float* __restrict__ sin_t, const float* __restrict__ cos_t,
                float* __restrict__ pkv) {
    // grid (NBH, 8)
    int bh = blockIdx.x, chunk = blockIdx.y;
    int b = bh / NH, h = bh % NH;
    int t = threadIdx.x, tx = t & 15, ty = t >> 4;
    __shared__ float Kt[32][64];
    __shared__ float Vt[32][64];
    float acc[4][4] = {};
    int n0 = chunk * KVROWS;
    int lr = t >> 3, lc = (t & 7) * 8;
    for (int nc = 0; nc < KVROWS; nc += 32) {
        int n = n0 + nc + lr;
        size_t off = ((size_t)b * N_SEQ + n) * C_DIM + h * HD + lc;
        size_t toff = (size_t)n * HD + lc;
        float4 k1 = *(const float4*)&Kb[off];
        float4 k2 = *(const float4*)&Kb[off + 4];
        float4 v1 = *(const float4*)&Vb[off];
        float4 v2 = *(const float4*)&Vb[off + 4];
        float4 s1 = *(const float4*)&sin_t[toff];
        float4 s2 = *(const float4*)&sin_t[toff + 4];
        float4 c1 = *(const float4*)&cos_t[toff];
        float4 c2 = *(const float4*)&cos_t[toff + 4];
        float4 kr1, kr2;
        kr1.x = k1.x * c1.x - k1.y * s1.x;
        kr1.y = k1.y * c1.y + k1.x * s1.y;
        kr1.z = k1.z * c1.z - k1.w * s1.z;
        kr1.w = k1.w * c1.w + k1.z * s1.w;
        kr2.x = k2.x * c2.x - k2.y * s2.x;
        kr2.y = k2.y * c2.y + k2.x * s2.y;
        kr2.z = k2.z * c2.z - k2.w * s2.z;
        kr2.w = k2.w * c2.w + k2.z * s2.w;
        __syncthreads();
        *(float4*)&Kt[lr][lc] = kr1; *(float4*)&Kt[lr][lc + 4] = kr2;
        *(float4*)&Vt[lr][lc] = v1;  *(float4*)&Vt[lr][lc + 4] = v2;
        __syncthreads();
        #pragma unroll
        for (int nn = 0; nn < 32; ++nn) {
            float a[4], bb[4];
            #pragma unroll
            for (int i = 0; i < 4; ++i) a[i] = Kt[nn][ty * 4 + i];
            #pragma unroll
            for (int j = 0; j < 4; ++j) bb[j] = Vt[nn][tx * 4 + j];
            #pragma unroll
            for (int i = 0; i < 4; ++i)
                #pragma unroll
                for (int j = 0; j < 4; ++j)
                    acc[i][j] += a[i] * bb[j];
        }
    }
    size_t obase = ((size_t)bh * 8 + chunk) * 4096;
    #pragma unroll
    for (int i = 0; i < 4; ++i)
        #pragma unroll
        for (int j = 0; j < 4; ++j)
            pkv[obase + (ty * 4 + i) * 64 + (tx * 4 + j)] = acc[i][j];
}

__global__ void kv_reduce(const float* __restrict__ pkv, float* __restrict__ kv) {
    int bh = blockIdx.x;  // 256 threads
    for (int u = threadIdx.x; u < 4096; u += 256) {
        float s = 0;
        for (int c = 0; c < 8; ++c) s += pkv[((size_t)bh * 8 + c) * 4096 + u];
        kv[(size_t)bh * 4096 + u] = s * (SCALE / N_SEQ);
    }
}

// ---------------- fused: z, rope(q), q@kv, rescale; in-place over Q ----------------
__global__ __launch_bounds__(256)
void res_kernel(float* __restrict__ Qb, const float* __restrict__ kv,
                const float* __restrict__ kmean, const float* __restrict__ vmean,
                const float* __restrict__ sin_t, const float* __restrict__ cos_t) {
    // grid (NBH, N_SEQ/16); wave w handles rows y*16 + w*4 + it
    int bh = blockIdx.x;
    int b = bh / NH, h = bh % NH;
    int w = threadIdx.x >> 6, lane = threadIdx.x & 63;
    __shared__ float kvs[4096];
    __shared__ float kms[64], vms[64];
    for (int u = threadIdx.x; u < 4096; u += 256) kvs[u] = kv[(size_t)bh * 4096 + u];
    if (threadIdx.x < 64) {
        kms[lane] = kmean[bh * 64 + lane];
        vms[lane] = vmean[bh * 64 + lane];
    }
    __syncthreads();
    for (int it = 0; it < 4; ++it) {
        int n = blockIdx.y * 16 + w * 4 + it;
        size_t off = ((size_t)b * N_SEQ + n) * C_DIM + h * HD + lane;
        float q = Qb[off];
        float zp = q * kms[lane];
        #pragma unroll
        for (int s = 32; s; s >>= 1) zp += __shfl_xor(zp, s);
        float z = zp * SCALE;
        float p = __shfl_xor(q, 1);
        float rot = (lane & 1) ? p : -p;
        size_t toff = (size_t)n * HD + lane;
        float qr = q * cos_t[toff] + rot * sin_t[toff];
        float rs = 0.f;
        #pragma unroll 16
        for (int dd = 0; dd < 64; ++dd) {
            float qd = __shfl(qr, dd);
            rs += qd * kvs[dd * 64 + lane];
        }
        float outv = rs * (1.0f + 1.0f / (z + 1e-6f)) - z * vms[lane];
        Qb[off] = outv;
    }
}

extern "C" void kernel_launch(void* const* d_in, const int* in_sizes, int n_in,
                              void* d_out, int out_size, void* d_ws, size_t ws_size,
                              hipStream_t stream) {
    const float* query = (const float*)d_in[0];
    const float* key   = (const float*)d_in[1];
    const float* value = (const float*)d_in[2];
    const float* Wq = (const float*)d_in[3];
    const float* bq = (const float*)d_in[4];
    const float* Wk = (const float*)d_in[5];
    const float* bk = (const float*)d_in[6];
    const float* Wv = (const float*)d_in[7];
    const float* bv = (const float*)d_in[8];
    const float* Wo = (const float*)d_in[9];
    const float* bo = (const float*)d_in[10];
    const int* dH = (const int*)d_in[11];
    const int* dW = (const int*)d_in[12];
    float* out = (float*)d_out;

    const int M = B_SZ * N_SEQ;       // 16384
    const size_t mc = (size_t)M * C_DIM;  // 12582912

    float* ws = (float*)d_ws;
    float* Qb    = ws;                 // mc
    float* Kb    = Qb + mc;            // mc
    float* Vb    = Kb + mc;            // mc
    float* sin_t = Vb + mc;            // N_SEQ*HD
    float* cos_t = sin_t + (size_t)N_SEQ * HD;
    float* pk    = cos_t + (size_t)N_SEQ * HD;   // NBH*16*64
    float* pv    = pk + NBH * 16 * 64;
    float* km    = pv + NBH * 16 * 64;           // NBH*64
    float* vm    = km + NBH * 64;
    float* pkv   = vm + NBH * 64;                // NBH*8*4096
    float* kvb   = pkv + (size_t)NBH * 8 * 4096; // NBH*4096

    // 1. rope tables
    rope_table_k<<<dim3((N_SEQ * HD + 255) / 256), dim3(256), 0, stream>>>(dH, dW, sin_t, cos_t);

    // 2-4. projections
    dim3 ggrid(C_DIM / BNT, M / BM);
    gemm_nt<1><<<ggrid, dim3(256), 0, stream>>>(query, Wq, bq, Qb, M, C_DIM, C_DIM);
    gemm_nt<1><<<ggrid, dim3(256), 0, stream>>>(key,   Wk, bk, Kb, M, C_DIM, C_DIM);
    gemm_nt<0><<<ggrid, dim3(256), 0, stream>>>(value, Wv, bv, Vb, M, C_DIM, C_DIM);

    // 5-6. column means (pre-rope K, V)
    colsum_partial<<<dim3(NBH, 16), dim3(256), 0, stream>>>(Kb, Vb, pk, pv);
    colsum_reduce<<<dim3(NBH), dim3(64), 0, stream>>>(pk, pv, km, vm);

    // 7-8. kv = rope(k)^T v
    kv_partial<<<dim3(NBH, 8), dim3(256), 0, stream>>>(Kb, Vb, sin_t, cos_t, pkv);
    kv_reduce<<<dim3(NBH), dim3(256), 0, stream>>>(pkv, kvb);

    // 9. fused z / rope(q) / q@kv / rescale (in-place into Qb)
    res_kernel<<<dim3(NBH, N_SEQ / 16), dim3(256), 0, stream>>>(Qb, kvb, km, vm, sin_t, cos_t);

    // 10. output projection
    gemm_nt<0><<<ggrid, dim3(256), 0, stream>>>(Qb, Wo, bo, out, M, C_DIM, C_DIM);
}

// Round 2
// 425.518 us; speedup vs baseline: 3.1476x; 3.1476x over previous
//
#include <hip/hip_runtime.h>
#include <math.h>

// Shapes fixed by setup_inputs: B=4, N=4096 (=64*64), C=768, h=12, d=64
#define B_SZ   4
#define N_SEQ  4096
#define C_DIM  768
#define NH     12
#define HD     64
#define NBH    (B_SZ*NH)
#define SCALE  0.125f
#define M_ROWS (B_SZ*N_SEQ)

typedef unsigned short u16;
typedef short bf16x8 __attribute__((ext_vector_type(8)));
typedef float f32x4 __attribute__((ext_vector_type(4)));
typedef u16 u16x8 __attribute__((ext_vector_type(8)));

__device__ __forceinline__ u16 f2bf(float f) {
    union { float f; unsigned u; } v; v.f = f;
    unsigned r = v.u + 0x7fffu + ((v.u >> 16) & 1u);
    return (u16)(r >> 16);
}
__device__ __forceinline__ float bf2f(u16 u) {
    union { unsigned u; float f; } v; v.u = ((unsigned)u) << 16;
    return v.f;
}

typedef const __attribute__((address_space(1))) void GLBV;
typedef __attribute__((address_space(3))) void LDSV;
#define GLDS(g, l) __builtin_amdgcn_global_load_lds((GLBV*)(g), (LDSV*)(l), 16, 0, 0)

// ---------------- fp32 -> bf16 converts ----------------
__global__ __launch_bounds__(256)
void cvt3(const float* __restrict__ a, const float* __restrict__ b, const float* __restrict__ c,
          u16* __restrict__ ao, u16* __restrict__ bo, u16* __restrict__ co) {
    size_t i = ((size_t)blockIdx.x * 256 + threadIdx.x) * 8;
    const float* srcs[3] = {a + i, b + i, c + i};
    u16* dsts[3] = {ao + i, bo + i, co + i};
    #pragma unroll
    for (int s = 0; s < 3; ++s) {
        float4 x = *(const float4*)srcs[s];
        float4 y = *(const float4*)(srcs[s] + 4);
        u16x8 o;
        o[0] = f2bf(x.x); o[1] = f2bf(x.y); o[2] = f2bf(x.z); o[3] = f2bf(x.w);
        o[4] = f2bf(y.x); o[5] = f2bf(y.y); o[6] = f2bf(y.z); o[7] = f2bf(y.w);
        *(u16x8*)dsts[s] = o;
    }
}

__global__ __launch_bounds__(256)
void cvt_w(const float* __restrict__ w0, const float* __restrict__ w1,
           const float* __restrict__ w2, const float* __restrict__ w3,
           u16* __restrict__ o0, u16* __restrict__ o1, u16* __restrict__ o2, u16* __restrict__ o3) {
    size_t i = ((size_t)blockIdx.x * 256 + threadIdx.x) * 8;
    const float* srcs[4] = {w0 + i, w1 + i, w2 + i, w3 + i};
    u16* dsts[4] = {o0 + i, o1 + i, o2 + i, o3 + i};
    #pragma unroll
    for (int s = 0; s < 4; ++s) {
        float4 x = *(const float4*)srcs[s];
        float4 y = *(const float4*)(srcs[s] + 4);
        u16x8 o;
        o[0] = f2bf(x.x); o[1] = f2bf(x.y); o[2] = f2bf(x.z); o[3] = f2bf(x.w);
        o[4] = f2bf(y.x); o[5] = f2bf(y.y); o[6] = f2bf(y.z); o[7] = f2bf(y.w);
        *(u16x8*)dsts[s] = o;
    }
}

// ---------------- rope tables (N_SEQ x 64), fp32 ----------------
__global__ void rope_table_k(const int* __restrict__ dH, const int* __restrict__ dW,
                             float* __restrict__ sin_t, float* __restrict__ cos_t) {
    int idx = blockIdx.x * 256 + threadIdx.x;
    if (idx >= N_SEQ * HD) return;
    int n = idx >> 6, j = idx & 63;
    int Wd = dW[0];
    int hh = n / Wd, ww = n % Wd;
    int jj = j & 31;
    float pos = (j < 32) ? (float)hh : (float)ww;
    float freq = powf(10000.0f, -((float)(jj >> 1) / 15.0f));
    float th = pos * freq;
    sin_t[idx] = sinf(th);
    cos_t[idx] = cosf(th);
}

// ---------------- bf16 MFMA GEMM (m97 structure): C = A[M][K] @ Bw[Nn][K]^T + bias ----------------
template<int ACT, typename OUT>
__global__ __launch_bounds__(256)
void gemm_mfma(const u16* __restrict__ A, const u16* __restrict__ Bw,
               const float* __restrict__ bias, OUT* __restrict__ Cc,
               int M, int Nn, int K) {
    __shared__ __align__(16) u16 As[4096];   // 128 rows x 32 k, row-major, linear (global_load_lds)
    __shared__ __align__(16) u16 Bs[4096];
    const int t = threadIdx.x;
    const int lane = t & 63, w = t >> 6;
    const int wr = w >> 1, wc = w & 1;          // wave tile 64x64 in 2x2 arrangement
    const int m0 = blockIdx.y * 128, n0 = blockIdx.x * 128;

    // staging: per round, 256 lanes x 16B = 4KB; 2 rounds per 8KB operand tile
    const int r0 = w * 16 + (lane >> 2);        // row within tile (round 0)
    const int c0 = (lane & 3) * 8;              // k-elem offset
    const u16* gA0 = A + (size_t)(m0 + r0) * K + c0;
    const u16* gA1 = A + (size_t)(m0 + 64 + r0) * K + c0;
    const u16* gB0 = Bw + (size_t)(n0 + r0) * K + c0;
    const u16* gB1 = Bw + (size_t)(n0 + 64 + r0) * K + c0;
    u16* lA0 = &As[w * 512]; u16* lA1 = &As[2048 + w * 512];
    u16* lB0 = &Bs[w * 512]; u16* lB1 = &Bs[2048 + w * 512];

    f32x4 acc[4][4] = {};

    const int ra = lane & 15, kg = (lane >> 4) * 8;
    for (int k0 = 0; k0 < K; k0 += 32) {
        __syncthreads();                         // previous compute done -> LDS free
        GLDS(gA0, lA0); GLDS(gA1, lA1);
        GLDS(gB0, lB0); GLDS(gB1, lB1);
        gA0 += 32; gA1 += 32; gB0 += 32; gB1 += 32;
        __syncthreads();                         // drains vmcnt -> tile visible
        bf16x8 av[4], bv[4];
        #pragma unroll
        for (int i = 0; i < 4; ++i)
            av[i] = *(const bf16x8*)&As[(wr * 64 + i * 16 + ra) * 32 + kg];
        #pragma unroll
        for (int j = 0; j < 4; ++j)
            bv[j] = *(const bf16x8*)&Bs[(wc * 64 + j * 16 + ra) * 32 + kg];
        #pragma unroll
        for (int i = 0; i < 4; ++i)
            #pragma unroll
            for (int j = 0; j < 4; ++j)
                asm("v_mfma_f32_16x16x32_bf16 %0, %1, %2, %0"
                    : "+v"(acc[i][j]) : "v"(av[i]), "v"(bv[j]));
    }

    // epilogue: C/D layout col=lane&15, row=(lane>>4)*4+reg (m89-verified)
    const int cr4 = (lane >> 4) * 4;
    const int ccc = lane & 15;
    #pragma unroll
    for (int j = 0; j < 4; ++j) {
        const int col = n0 + wc * 64 + j * 16 + ccc;
        const float bj = bias[col];
        #pragma unroll
        for (int i = 0; i < 4; ++i) {
            const int row = m0 + wr * 64 + i * 16 + cr4;
            #pragma unroll
            for (int r = 0; r < 4; ++r) {
                float v = acc[i][j][r] + bj;
                if (ACT) v = (v > 0.f) ? (v + 1.f) : __expf(v);  // elu+1
                if constexpr (sizeof(OUT) == 2)
                    Cc[(size_t)(row + r) * Nn + col] = (OUT)f2bf(v);
                else
                    Cc[(size_t)(row + r) * Nn + col] = v;
            }
        }
    }
}

// ---------------- column sums (post-act K, raw V), bf16 in, fp32 partials ----------------
__global__ __launch_bounds__(256)
void colsum_partial(const u16* __restrict__ Kb, const u16* __restrict__ Vb,
                    float* __restrict__ pk, float* __restrict__ pv) {
    int bh = blockIdx.x, chunk = blockIdx.y;
    int b = bh / NH, h = bh % NH;
    int w = threadIdx.x >> 6, lane = threadIdx.x & 63;
    size_t base = ((size_t)b * N_SEQ) * C_DIM + (size_t)h * HD + lane;
    int n0 = chunk * 256;
    float sk = 0.f, sv = 0.f;
    for (int it = 0; it < 64; ++it) {
        int n = n0 + w + 4 * it;
        size_t off = base + (size_t)n * C_DIM;
        sk += bf2f(Kb[off]);
        sv += bf2f(Vb[off]);
    }
    __shared__ float red[2][4][64];
    red[0][w][lane] = sk; red[1][w][lane] = sv;
    __syncthreads();
    if (threadIdx.x < 64) {
        float k4 = red[0][0][lane] + red[0][1][lane] + red[0][2][lane] + red[0][3][lane];
        float v4 = red[1][0][lane] + red[1][1][lane] + red[1][2][lane] + red[1][3][lane];
        pk[(bh * 16 + chunk) * 64 + lane] = k4;
        pv[(bh * 16 + chunk) * 64 + lane] = v4;
    }
}

__global__ void colsum_reduce(const float* __restrict__ pk, const float* __restrict__ pv,
                              float* __restrict__ kmean, float* __restrict__ vmean) {
    int bh = blockIdx.x, lane = threadIdx.x;  // 64 threads
    float sk = 0, sv = 0;
    for (int c = 0; c < 16; ++c) {
        sk += pk[(bh * 16 + c) * 64 + lane];
        sv += pv[(bh * 16 + c) * 64 + lane];
    }
    kmean[bh * 64 + lane] = sk * (1.0f / N_SEQ);
    vmean[bh * 64 + lane] = sv * (1.0f / N_SEQ);
}

// ---------------- kv = sum_n rope(k)[n] (x) v[n], bf16 in, fp32 out ----------------
#define KVROWS 512
__global__ __launch_bounds__(256)
void kv_partial(const u16* __restrict__ Kb, const u16* __restrict__ Vb,
                const float* __restrict__ sin_t, const float* __restrict__ cos_t,
                float* __restrict__ pkv) {
    int bh = blockIdx.x, chunk = blockIdx.y;
    int b = bh / NH, h = bh % NH;
    int t = threadIdx.x, tx = t & 15, ty = t >> 4;
    __shared__ float Kt[32][64];
    __shared__ float Vt[32][64];
    float acc[4][4] = {};
    int n0 = chunk * KVROWS;
    int lr = t >> 3, lc = (t & 7) * 8;
    for (int nc = 0; nc < KVROWS; nc += 32) {
        int n = n0 + nc + lr;
        size_t off = ((size_t)b * N_SEQ + n) * C_DIM + h * HD + lc;
        size_t toff = (size_t)n * HD + lc;
        u16x8 k8 = *(const u16x8*)&Kb[off];
        u16x8 v8 = *(const u16x8*)&Vb[off];
        float kf[8], vf[8], sn[8], cs[8];
        #pragma unroll
        for (int i = 0; i < 8; ++i) { kf[i] = bf2f(k8[i]); vf[i] = bf2f(v8[i]); }
        float4 s1 = *(const float4*)&sin_t[toff];
        float4 s2 = *(const float4*)&sin_t[toff + 4];
        float4 c1 = *(const float4*)&cos_t[toff];
        float4 c2 = *(const float4*)&cos_t[toff + 4];
        sn[0]=s1.x; sn[1]=s1.y; sn[2]=s1.z; sn[3]=s1.w; sn[4]=s2.x; sn[5]=s2.y; sn[6]=s2.z; sn[7]=s2.w;
        cs[0]=c1.x; cs[1]=c1.y; cs[2]=c1.z; cs[3]=c1.w; cs[4]=c2.x; cs[5]=c2.y; cs[6]=c2.z; cs[7]=c2.w;
        float kr[8];
        #pragma unroll
        for (int e = 0; e < 8; e += 2) {
            kr[e]   = kf[e] * cs[e]   - kf[e+1] * sn[e];
            kr[e+1] = kf[e+1] * cs[e+1] + kf[e] * sn[e+1];
        }
        __syncthreads();
        #pragma unroll
        for (int i = 0; i < 8; ++i) { Kt[lr][lc + i] = kr[i]; Vt[lr][lc + i] = vf[i]; }
        __syncthreads();
        #pragma unroll
        for (int nn = 0; nn < 32; ++nn) {
            float a[4], bb[4];
            #pragma unroll
            for (int i = 0; i < 4; ++i) a[i] = Kt[nn][ty * 4 + i];
            #pragma unroll
            for (int j = 0; j < 4; ++j) bb[j] = Vt[nn][tx * 4 + j];
            #pragma unroll
            for (int i = 0; i < 4; ++i)
                #pragma unroll
                for (int j = 0; j < 4; ++j)
                    acc[i][j] += a[i] * bb[j];
        }
    }
    size_t obase = ((size_t)bh * 8 + chunk) * 4096;
    #pragma unroll
    for (int i = 0; i < 4; ++i)
        #pragma unroll
        for (int j = 0; j < 4; ++j)
            pkv[obase + (ty * 4 + i) * 64 + (tx * 4 + j)] = acc[i][j];
}

__global__ void kv_reduce(const float* __restrict__ pkv, float* __restrict__ kv) {
    int bh = blockIdx.x;  // 256 threads
    for (int u = threadIdx.x; u < 4096; u += 256) {
        float s = 0;
        for (int c = 0; c < 8; ++c) s += pkv[((size_t)bh * 8 + c) * 4096 + u];
        kv[(size_t)bh * 4096 + u] = s * (SCALE / N_SEQ);
    }
}

// ---------------- fused: z, rope(q), q@kv, rescale; bf16 in -> bf16 out ----------------
__global__ __launch_bounds__(256)
void res_kernel(const u16* __restrict__ Qb, u16* __restrict__ Rb,
                const float* __restrict__ kv,
                const float* __restrict__ kmean, const float* __restrict__ vmean,
                const float* __restrict__ sin_t, const float* __restrict__ cos_t) {
    int bh = blockIdx.x;
    int b = bh / NH, h = bh % NH;
    int w = threadIdx.x >> 6, lane = threadIdx.x & 63;
    __shared__ float kvs[4096];
    __shared__ float kms[64], vms[64];
    for (int u = threadIdx.x; u < 4096; u += 256) kvs[u] = kv[(size_t)bh * 4096 + u];
    if (threadIdx.x < 64) {
        kms[lane] = kmean[bh * 64 + lane];
        vms[lane] = vmean[bh * 64 + lane];
    }
    __syncthreads();
    for (int it = 0; it < 4; ++it) {
        int n = blockIdx.y * 16 + w * 4 + it;
        size_t off = ((size_t)b * N_SEQ + n) * C_DIM + (size_t)h * HD + lane;
        float q = bf2f(Qb[off]);
        float zp = q * kms[lane];
        #pragma unroll
        for (int s = 32; s; s >>= 1) zp += __shfl_xor(zp, s);
        float z = zp * SCALE;
        float p = __shfl_xor(q, 1);
        float rot = (lane & 1) ? p : -p;
        size_t toff = (size_t)n * HD + lane;
        float qr = q * cos_t[toff] + rot * sin_t[toff];
        float rs = 0.f;
        #pragma unroll 16
        for (int dd = 0; dd < 64; ++dd) {
            float qd = __shfl(qr, dd);
            rs += qd * kvs[dd * 64 + lane];
        }
        float outv = rs * (1.0f + 1.0f / (z + 1e-6f)) - z * vms[lane];
        Rb[off] = f2bf(outv);
    }
}

extern "C" void kernel_launch(void* const* d_in, const int* in_sizes, int n_in,
                              void* d_out, int out_size, void* d_ws, size_t ws_size,
                              hipStream_t stream) {
    const float* query = (const float*)d_in[0];
    const float* key   = (const float*)d_in[1];
    const float* value = (const float*)d_in[2];
    const float* Wq = (const float*)d_in[3];
    const float* bq = (const float*)d_in[4];
    const float* Wk = (const float*)d_in[5];
    const float* bk = (const float*)d_in[6];
    const float* Wv = (const float*)d_in[7];
    const float* bv = (const float*)d_in[8];
    const float* Wo = (const float*)d_in[9];
    const float* bo = (const float*)d_in[10];
    const int* dH = (const int*)d_in[11];
    const int* dW = (const int*)d_in[12];
    float* out = (float*)d_out;

    const size_t mc = (size_t)M_ROWS * C_DIM;   // 12,582,912
    const size_t wsz = (size_t)C_DIM * C_DIM;   // 589,824

    // bf16 buffers
    u16* ws16 = (u16*)d_ws;
    u16* qc  = ws16;             // mc  (also reused as Rb)
    u16* kc  = qc + mc;          // mc
    u16* vc  = kc + mc;          // mc
    u16* Qb  = vc + mc;          // mc
    u16* Kb  = Qb + mc;          // mc
    u16* Vb  = Kb + mc;          // mc
    u16* wqb = Vb + mc;          // wsz
    u16* wkb = wqb + wsz;
    u16* wvb = wkb + wsz;
    u16* wob = wvb + wsz;
    u16* Rb  = qc;               // alias: qc dead after Q-projection

    // fp32 buffers
    float* wsf = (float*)(wob + wsz);
    float* sin_t = wsf;                          // 262144
    float* cos_t = sin_t + (size_t)N_SEQ * HD;   // 262144
    float* pk    = cos_t + (size_t)N_SEQ * HD;   // 49152
    float* pv    = pk + NBH * 16 * 64;
    float* km    = pv + NBH * 16 * 64;           // 3072
    float* vm    = km + NBH * 64;
    float* pkv   = vm + NBH * 64;                // 1572864
    float* kvb   = pkv + (size_t)NBH * 8 * 4096; // 196608

    // converts + tables
    cvt3<<<dim3(6144), dim3(256), 0, stream>>>(query, key, value, qc, kc, vc);
    cvt_w<<<dim3(288), dim3(256), 0, stream>>>(Wq, Wk, Wv, Wo, wqb, wkb, wvb, wob);
    rope_table_k<<<dim3(1024), dim3(256), 0, stream>>>(dH, dW, sin_t, cos_t);

    // projections (bf16 MFMA)
    dim3 gg(C_DIM / 128, M_ROWS / 128);
    gemm_mfma<1, u16><<<gg, dim3(256), 0, stream>>>(qc, wqb, bq, Qb, M_ROWS, C_DIM, C_DIM);
    gemm_mfma<1, u16><<<gg, dim3(256), 0, stream>>>(kc, wkb, bk, Kb, M_ROWS, C_DIM, C_DIM);
    gemm_mfma<0, u16><<<gg, dim3(256), 0, stream>>>(vc, wvb, bv, Vb, M_ROWS, C_DIM, C_DIM);

    // means
    colsum_partial<<<dim3(NBH, 16), dim3(256), 0, stream>>>(Kb, Vb, pk, pv);
    colsum_reduce<<<dim3(NBH), dim3(64), 0, stream>>>(pk, pv, km, vm);

    // kv
    kv_partial<<<dim3(NBH, 8), dim3(256), 0, stream>>>(Kb, Vb, sin_t, cos_t, pkv);
    kv_reduce<<<dim3(NBH), dim3(256), 0, stream>>>(pkv, kvb);

    // fused middle
    res_kernel<<<dim3(NBH, N_SEQ / 16), dim3(256), 0, stream>>>(Qb, Rb, kvb, km, vm, sin_t, cos_t);

    // output projection (fp32 out)
    gemm_mfma<0, float><<<gg, dim3(256), 0, stream>>>(Rb, wob, bo, out, M_ROWS, C_DIM, C_DIM);
}

// Round 3
// 261.454 us; speedup vs baseline: 5.1228x; 1.6275x over previous
//
#include <hip/hip_runtime.h>
#include <math.h>

// Shapes fixed by setup_inputs: B=4, N=4096 (=64*64), C=768, h=12, d=64
#define B_SZ   4
#define N_SEQ  4096
#define C_DIM  768
#define NH     12
#define HD     64
#define NBH    (B_SZ*NH)
#define SCALE  0.125f
#define M_ROWS (B_SZ*N_SEQ)

typedef unsigned short u16;
typedef short bf16x8 __attribute__((ext_vector_type(8)));
typedef float f32x4 __attribute__((ext_vector_type(4)));
typedef u16 u16x8 __attribute__((ext_vector_type(8)));

__device__ __forceinline__ u16 f2bf(float f) {
    union { float f; unsigned u; } v; v.f = f;
    unsigned r = v.u + 0x7fffu + ((v.u >> 16) & 1u);
    return (u16)(r >> 16);
}
__device__ __forceinline__ float bf2f(u16 u) {
    union { unsigned u; float f; } v; v.u = ((unsigned)u) << 16;
    return v.f;
}

typedef const __attribute__((address_space(1))) void GLBV;
typedef __attribute__((address_space(3))) void LDSV;
#define GLDS(g, l) __builtin_amdgcn_global_load_lds((GLBV*)(g), (LDSV*)(l), 16, 0, 0)

// ---------------- fp32 -> bf16 converts ----------------
__global__ __launch_bounds__(256)
void cvt3(const float* __restrict__ a, const float* __restrict__ b, const float* __restrict__ c,
          u16* __restrict__ ao, u16* __restrict__ bo, u16* __restrict__ co) {
    size_t i = ((size_t)blockIdx.x * 256 + threadIdx.x) * 8;
    const float* srcs[3] = {a + i, b + i, c + i};
    u16* dsts[3] = {ao + i, bo + i, co + i};
    #pragma unroll
    for (int s = 0; s < 3; ++s) {
        float4 x = *(const float4*)srcs[s];
        float4 y = *(const float4*)(srcs[s] + 4);
        u16x8 o;
        o[0] = f2bf(x.x); o[1] = f2bf(x.y); o[2] = f2bf(x.z); o[3] = f2bf(x.w);
        o[4] = f2bf(y.x); o[5] = f2bf(y.y); o[6] = f2bf(y.z); o[7] = f2bf(y.w);
        *(u16x8*)dsts[s] = o;
    }
}

__global__ __launch_bounds__(256)
void cvt_w(const float* __restrict__ w0, const float* __restrict__ w1,
           const float* __restrict__ w2, const float* __restrict__ w3,
           u16* __restrict__ o0, u16* __restrict__ o1, u16* __restrict__ o2, u16* __restrict__ o3) {
    size_t i = ((size_t)blockIdx.x * 256 + threadIdx.x) * 8;
    const float* srcs[4] = {w0 + i, w1 + i, w2 + i, w3 + i};
    u16* dsts[4] = {o0 + i, o1 + i, o2 + i, o3 + i};
    #pragma unroll
    for (int s = 0; s < 4; ++s) {
        float4 x = *(const float4*)srcs[s];
        float4 y = *(const float4*)(srcs[s] + 4);
        u16x8 o;
        o[0] = f2bf(x.x); o[1] = f2bf(x.y); o[2] = f2bf(x.z); o[3] = f2bf(x.w);
        o[4] = f2bf(y.x); o[5] = f2bf(y.y); o[6] = f2bf(y.z); o[7] = f2bf(y.w);
        *(u16x8*)dsts[s] = o;
    }
}

// ---------------- rope tables (N_SEQ x 64), fp32 ----------------
__global__ void rope_table_k(const int* __restrict__ dH, const int* __restrict__ dW,
                             float* __restrict__ sin_t, float* __restrict__ cos_t) {
    int idx = blockIdx.x * 256 + threadIdx.x;
    if (idx >= N_SEQ * HD) return;
    int n = idx >> 6, j = idx & 63;
    int Wd = dW[0];
    int hh = n / Wd, ww = n % Wd;
    int jj = j & 31;
    float pos = (j < 32) ? (float)hh : (float)ww;
    float freq = powf(10000.0f, -((float)(jj >> 1) / 15.0f));
    float th = pos * freq;
    sin_t[idx] = sinf(th);
    cos_t[idx] = cosf(th);
}

// ---------------- bf16 MFMA GEMM (m97 structure): C = A[M][K] @ Bw[Nn][K]^T + bias ----------------
template<int ACT, typename OUT>
__global__ __launch_bounds__(256)
void gemm_mfma(const u16* __restrict__ A, const u16* __restrict__ Bw,
               const float* __restrict__ bias, OUT* __restrict__ Cc,
               int M, int Nn, int K) {
    __shared__ __align__(16) u16 As[4096];   // 128 rows x 32 k, row-major, linear (global_load_lds)
    __shared__ __align__(16) u16 Bs[4096];
    const int t = threadIdx.x;
    const int lane = t & 63, w = t >> 6;
    const int wr = w >> 1, wc = w & 1;          // wave tile 64x64 in 2x2 arrangement
    const int m0 = blockIdx.y * 128, n0 = blockIdx.x * 128;

    const int r0 = w * 16 + (lane >> 2);
    const int c0 = (lane & 3) * 8;
    const u16* gA0 = A + (size_t)(m0 + r0) * K + c0;
    const u16* gA1 = A + (size_t)(m0 + 64 + r0) * K + c0;
    const u16* gB0 = Bw + (size_t)(n0 + r0) * K + c0;
    const u16* gB1 = Bw + (size_t)(n0 + 64 + r0) * K + c0;
    u16* lA0 = &As[w * 512]; u16* lA1 = &As[2048 + w * 512];
    u16* lB0 = &Bs[w * 512]; u16* lB1 = &Bs[2048 + w * 512];

    f32x4 acc[4][4] = {};

    const int ra = lane & 15, kg = (lane >> 4) * 8;
    for (int k0 = 0; k0 < K; k0 += 32) {
        __syncthreads();
        GLDS(gA0, lA0); GLDS(gA1, lA1);
        GLDS(gB0, lB0); GLDS(gB1, lB1);
        gA0 += 32; gA1 += 32; gB0 += 32; gB1 += 32;
        __syncthreads();
        bf16x8 av[4], bv[4];
        #pragma unroll
        for (int i = 0; i < 4; ++i)
            av[i] = *(const bf16x8*)&As[(wr * 64 + i * 16 + ra) * 32 + kg];
        #pragma unroll
        for (int j = 0; j < 4; ++j)
            bv[j] = *(const bf16x8*)&Bs[(wc * 64 + j * 16 + ra) * 32 + kg];
        #pragma unroll
        for (int i = 0; i < 4; ++i)
            #pragma unroll
            for (int j = 0; j < 4; ++j)
                asm("v_mfma_f32_16x16x32_bf16 %0, %1, %2, %0"
                    : "+v"(acc[i][j]) : "v"(av[i]), "v"(bv[j]));
    }

    const int cr4 = (lane >> 4) * 4;
    const int ccc = lane & 15;
    #pragma unroll
    for (int j = 0; j < 4; ++j) {
        const int col = n0 + wc * 64 + j * 16 + ccc;
        const float bj = bias[col];
        #pragma unroll
        for (int i = 0; i < 4; ++i) {
            const int row = m0 + wr * 64 + i * 16 + cr4;
            #pragma unroll
            for (int r = 0; r < 4; ++r) {
                float v = acc[i][j][r] + bj;
                if (ACT) v = (v > 0.f) ? (v + 1.f) : __expf(v);  // elu+1
                if constexpr (sizeof(OUT) == 2)
                    Cc[(size_t)(row + r) * Nn + col] = (OUT)f2bf(v);
                else
                    Cc[(size_t)(row + r) * Nn + col] = v;
            }
        }
    }
}

// ---------------- column sums (post-act K, raw V), bf16 in, fp32 partials ----------------
__global__ __launch_bounds__(256)
void colsum_partial(const u16* __restrict__ Kb, const u16* __restrict__ Vb,
                    float* __restrict__ pk, float* __restrict__ pv) {
    int bh = blockIdx.x, chunk = blockIdx.y;
    int b = bh / NH, h = bh % NH;
    int w = threadIdx.x >> 6, lane = threadIdx.x & 63;
    size_t base = ((size_t)b * N_SEQ) * C_DIM + (size_t)h * HD + lane;
    int n0 = chunk * 256;
    float sk = 0.f, sv = 0.f;
    for (int it = 0; it < 64; ++it) {
        int n = n0 + w + 4 * it;
        size_t off = base + (size_t)n * C_DIM;
        sk += bf2f(Kb[off]);
        sv += bf2f(Vb[off]);
    }
    __shared__ float red[2][4][64];
    red[0][w][lane] = sk; red[1][w][lane] = sv;
    __syncthreads();
    if (threadIdx.x < 64) {
        float k4 = red[0][0][lane] + red[0][1][lane] + red[0][2][lane] + red[0][3][lane];
        float v4 = red[1][0][lane] + red[1][1][lane] + red[1][2][lane] + red[1][3][lane];
        pk[(bh * 16 + chunk) * 64 + lane] = k4;
        pv[(bh * 16 + chunk) * 64 + lane] = v4;
    }
}

__global__ void colsum_reduce(const float* __restrict__ pk, const float* __restrict__ pv,
                              float* __restrict__ kmean, float* __restrict__ vmean) {
    int bh = blockIdx.x, lane = threadIdx.x;  // 64 threads
    float sk = 0, sv = 0;
    for (int c = 0; c < 16; ++c) {
        sk += pk[(bh * 16 + c) * 64 + lane];
        sv += pv[(bh * 16 + c) * 64 + lane];
    }
    kmean[bh * 64 + lane] = sk * (1.0f / N_SEQ);
    vmean[bh * 64 + lane] = sv * (1.0f / N_SEQ);
}

// ---------------- kv = sum_n rope(k)[n] (x) v[n], bf16 in, fp32 partials ----------------
#define KVROWS 512
__global__ __launch_bounds__(256)
void kv_partial(const u16* __restrict__ Kb, const u16* __restrict__ Vb,
                const float* __restrict__ sin_t, const float* __restrict__ cos_t,
                float* __restrict__ pkv) {
    int bh = blockIdx.x, chunk = blockIdx.y;
    int b = bh / NH, h = bh % NH;
    int t = threadIdx.x, tx = t & 15, ty = t >> 4;
    __shared__ float Kt[32][64];
    __shared__ float Vt[32][64];
    float acc[4][4] = {};
    int n0 = chunk * KVROWS;
    int lr = t >> 3, lc = (t & 7) * 8;
    for (int nc = 0; nc < KVROWS; nc += 32) {
        int n = n0 + nc + lr;
        size_t off = ((size_t)b * N_SEQ + n) * C_DIM + h * HD + lc;
        size_t toff = (size_t)n * HD + lc;
        u16x8 k8 = *(const u16x8*)&Kb[off];
        u16x8 v8 = *(const u16x8*)&Vb[off];
        float kf[8], vf[8], sn[8], cs[8];
        #pragma unroll
        for (int i = 0; i < 8; ++i) { kf[i] = bf2f(k8[i]); vf[i] = bf2f(v8[i]); }
        float4 s1 = *(const float4*)&sin_t[toff];
        float4 s2 = *(const float4*)&sin_t[toff + 4];
        float4 c1 = *(const float4*)&cos_t[toff];
        float4 c2 = *(const float4*)&cos_t[toff + 4];
        sn[0]=s1.x; sn[1]=s1.y; sn[2]=s1.z; sn[3]=s1.w; sn[4]=s2.x; sn[5]=s2.y; sn[6]=s2.z; sn[7]=s2.w;
        cs[0]=c1.x; cs[1]=c1.y; cs[2]=c1.z; cs[3]=c1.w; cs[4]=c2.x; cs[5]=c2.y; cs[6]=c2.z; cs[7]=c2.w;
        float kr[8];
        #pragma unroll
        for (int e = 0; e < 8; e += 2) {
            kr[e]   = kf[e] * cs[e]   - kf[e+1] * sn[e];
            kr[e+1] = kf[e+1] * cs[e+1] + kf[e] * sn[e+1];
        }
        __syncthreads();
        #pragma unroll
        for (int i = 0; i < 8; ++i) { Kt[lr][lc + i] = kr[i]; Vt[lr][lc + i] = vf[i]; }
        __syncthreads();
        #pragma unroll
        for (int nn = 0; nn < 32; ++nn) {
            float a[4], bb[4];
            #pragma unroll
            for (int i = 0; i < 4; ++i) a[i] = Kt[nn][ty * 4 + i];
            #pragma unroll
            for (int j = 0; j < 4; ++j) bb[j] = Vt[nn][tx * 4 + j];
            #pragma unroll
            for (int i = 0; i < 4; ++i)
                #pragma unroll
                for (int j = 0; j < 4; ++j)
                    acc[i][j] += a[i] * bb[j];
        }
    }
    size_t obase = ((size_t)bh * 8 + chunk) * 4096;
    #pragma unroll
    for (int i = 0; i < 4; ++i)
        #pragma unroll
        for (int j = 0; j < 4; ++j)
            pkv[obase + (ty * 4 + i) * 64 + (tx * 4 + j)] = acc[i][j];
}

// reduce partials, scale, emit TRANSPOSED bf16 hi/lo pair: kvT16[bh][p][e][d]
__global__ void kv_reduce(const float* __restrict__ pkv, u16* __restrict__ kvT16) {
    int bh = blockIdx.x;  // 256 threads
    for (int u = threadIdx.x; u < 4096; u += 256) {
        float s = 0;
        for (int c = 0; c < 8; ++c) s += pkv[((size_t)bh * 8 + c) * 4096 + u];
        s *= (SCALE / N_SEQ);
        int d = u >> 6, e = u & 63;
        u16 hi = f2bf(s);
        u16 lo = f2bf(s - bf2f(hi));
        kvT16[(size_t)bh * 8192 + e * 64 + d] = hi;
        kvT16[(size_t)bh * 8192 + 4096 + e * 64 + d] = lo;
    }
}

// ---------------- fused res: z + rope(q) + MFMA(q @ kv) + rescale ----------------
#define LDQ 72   // pad 64 -> 72: frag-read stride 144B => ~2-way bank alias (free, m136)
__global__ __launch_bounds__(256)
void res_mfma(const u16* __restrict__ Qb, u16* __restrict__ Rb,
              const u16* __restrict__ kvT16,
              const float* __restrict__ kmean, const float* __restrict__ vmean,
              const float* __restrict__ sin_t, const float* __restrict__ cos_t) {
    // grid (NBH, N_SEQ/128); block = 256 = 4 waves; wave w -> rows w*32..w*32+31
    __shared__ __align__(16) u16 qs[128 * LDQ];
    __shared__ __align__(16) u16 kvs[2][64 * LDQ];   // hi, lo
    __shared__ float zs[128];
    __shared__ float kms[64], vms[64];
    const int bh = blockIdx.x;
    const int b = bh / NH, h = bh % NH;
    const int n0 = blockIdx.y * 128;
    const int t = threadIdx.x;
    const int lane = t & 63, w = t >> 6;

    // stage kv^T hi/lo (2 x 64x64 bf16)
    {
        const int r = t >> 2, c = (t & 3) * 16;
        #pragma unroll
        for (int p = 0; p < 2; ++p) {
            size_t g = (size_t)bh * 8192 + p * 4096 + r * 64 + c;
            *(u16x8*)&kvs[p][r * LDQ + c]     = *(const u16x8*)&kvT16[g];
            *(u16x8*)&kvs[p][r * LDQ + c + 8] = *(const u16x8*)&kvT16[g + 8];
        }
    }
    if (t < 64) kms[t] = kmean[bh * 64 + t];
    else if (t < 128) vms[t - 64] = vmean[bh * 64 + (t - 64)];
    __syncthreads();

    // stage q: load bf16, compute z (pre-rope), rope, write bf16 to LDS
    #pragma unroll
    for (int ri = 0; ri < 4; ++ri) {
        const int row = ri * 32 + (t >> 3);
        const int c = (t & 7) * 8;
        const int n = n0 + row;
        size_t off = ((size_t)b * N_SEQ + n) * C_DIM + (size_t)h * HD + c;
        u16x8 q8 = *(const u16x8*)&Qb[off];
        float qf[8];
        #pragma unroll
        for (int i = 0; i < 8; ++i) qf[i] = bf2f(q8[i]);
        float zp = 0.f;
        #pragma unroll
        for (int i = 0; i < 8; ++i) zp += qf[i] * kms[c + i];
        zp += __shfl_xor(zp, 1); zp += __shfl_xor(zp, 2); zp += __shfl_xor(zp, 4);
        if ((t & 7) == 0) zs[row] = zp * SCALE;
        size_t toff = (size_t)n * HD + c;
        float4 s1 = *(const float4*)&sin_t[toff];
        float4 s2 = *(const float4*)&sin_t[toff + 4];
        float4 c1 = *(const float4*)&cos_t[toff];
        float4 c2 = *(const float4*)&cos_t[toff + 4];
        float sn[8] = {s1.x, s1.y, s1.z, s1.w, s2.x, s2.y, s2.z, s2.w};
        float cs[8] = {c1.x, c1.y, c1.z, c1.w, c2.x, c2.y, c2.z, c2.w};
        u16x8 qr8;
        #pragma unroll
        for (int e = 0; e < 8; e += 2) {
            qr8[e]   = f2bf(qf[e] * cs[e]     - qf[e+1] * sn[e]);
            qr8[e+1] = f2bf(qf[e+1] * cs[e+1] + qf[e]   * sn[e+1]);
        }
        *(u16x8*)&qs[row * LDQ + c] = qr8;
    }
    __syncthreads();

    // MFMA: rows 32/wave x cols 64, K=64, kv hi+lo both accumulated
    f32x4 acc[2][4] = {};
    const int ra = lane & 15, kg = (lane >> 4) * 8;
    #pragma unroll
    for (int p = 0; p < 2; ++p) {
        #pragma unroll
        for (int hh = 0; hh < 2; ++hh) {
            bf16x8 bv[4];
            #pragma unroll
            for (int j = 0; j < 4; ++j)
                bv[j] = *(const bf16x8*)&kvs[p][(j * 16 + ra) * LDQ + hh * 32 + kg];
            #pragma unroll
            for (int i = 0; i < 2; ++i) {
                bf16x8 av = *(const bf16x8*)&qs[(w * 32 + i * 16 + ra) * LDQ + hh * 32 + kg];
                #pragma unroll
                for (int j = 0; j < 4; ++j)
                    asm("v_mfma_f32_16x16x32_bf16 %0, %1, %2, %0"
                        : "+v"(acc[i][j]) : "v"(av), "v"(bv[j]));
            }
        }
    }

    // epilogue: res = acc*(1+1/(z+eps)) - z*vm
    const int cr4 = (lane >> 4) * 4, cc = lane & 15;
    #pragma unroll
    for (int i = 0; i < 2; ++i) {
        #pragma unroll
        for (int j = 0; j < 4; ++j) {
            const int col = j * 16 + cc;
            const float vmc = vms[col];
            #pragma unroll
            for (int r = 0; r < 4; ++r) {
                const int row = w * 32 + i * 16 + cr4 + r;
                const float z = zs[row];
                const float v = acc[i][j][r] * (1.0f + 1.0f / (z + 1e-6f)) - z * vmc;
                Rb[((size_t)b * N_SEQ + n0 + row) * C_DIM + (size_t)h * HD + col] = f2bf(v);
            }
        }
    }
}

extern "C" void kernel_launch(void* const* d_in, const int* in_sizes, int n_in,
                              void* d_out, int out_size, void* d_ws, size_t ws_size,
                              hipStream_t stream) {
    const float* query = (const float*)d_in[0];
    const float* key   = (const float*)d_in[1];
    const float* value = (const float*)d_in[2];
    const float* Wq = (const float*)d_in[3];
    const float* bq = (const float*)d_in[4];
    const float* Wk = (const float*)d_in[5];
    const float* bk = (const float*)d_in[6];
    const float* Wv = (const float*)d_in[7];
    const float* bv = (const float*)d_in[8];
    const float* Wo = (const float*)d_in[9];
    const float* bo = (const float*)d_in[10];
    const int* dH = (const int*)d_in[11];
    const int* dW = (const int*)d_in[12];
    float* out = (float*)d_out;

    const size_t mc = (size_t)M_ROWS * C_DIM;   // 12,582,912
    const size_t wsz = (size_t)C_DIM * C_DIM;   // 589,824

    // bf16 buffers
    u16* ws16 = (u16*)d_ws;
    u16* qc  = ws16;             // mc  (reused as Rb after Q-projection consumes it)
    u16* kc  = qc + mc;          // mc
    u16* vc  = kc + mc;          // mc
    u16* Qb  = vc + mc;          // mc
    u16* Kb  = Qb + mc;          // mc
    u16* Vb  = Kb + mc;          // mc
    u16* wqb = Vb + mc;          // wsz
    u16* wkb = wqb + wsz;
    u16* wvb = wkb + wsz;
    u16* wob = wvb + wsz;
    u16* kvT16 = wob + wsz;      // NBH * 8192 (hi + lo, transposed)
    u16* Rb  = qc;               // alias

    // fp32 buffers
    float* wsf = (float*)(kvT16 + (size_t)NBH * 8192);
    float* sin_t = wsf;                          // 262144
    float* cos_t = sin_t + (size_t)N_SEQ * HD;   // 262144
    float* pk    = cos_t + (size_t)N_SEQ * HD;   // 49152
    float* pv    = pk + NBH * 16 * 64;
    float* km    = pv + NBH * 16 * 64;           // 3072
    float* vm    = km + NBH * 64;
    float* pkv   = vm + NBH * 64;                // 1572864

    // converts + tables
    cvt3<<<dim3(6144), dim3(256), 0, stream>>>(query, key, value, qc, kc, vc);
    cvt_w<<<dim3(288), dim3(256), 0, stream>>>(Wq, Wk, Wv, Wo, wqb, wkb, wvb, wob);
    rope_table_k<<<dim3(1024), dim3(256), 0, stream>>>(dH, dW, sin_t, cos_t);

    // projections (bf16 MFMA)
    dim3 gg(C_DIM / 128, M_ROWS / 128);
    gemm_mfma<1, u16><<<gg, dim3(256), 0, stream>>>(qc, wqb, bq, Qb, M_ROWS, C_DIM, C_DIM);
    gemm_mfma<1, u16><<<gg, dim3(256), 0, stream>>>(kc, wkb, bk, Kb, M_ROWS, C_DIM, C_DIM);
    gemm_mfma<0, u16><<<gg, dim3(256), 0, stream>>>(vc, wvb, bv, Vb, M_ROWS, C_DIM, C_DIM);

    // means
    colsum_partial<<<dim3(NBH, 16), dim3(256), 0, stream>>>(Kb, Vb, pk, pv);
    colsum_reduce<<<dim3(NBH), dim3(64), 0, stream>>>(pk, pv, km, vm);

    // kv
    kv_partial<<<dim3(NBH, 8), dim3(256), 0, stream>>>(Kb, Vb, sin_t, cos_t, pkv);
    kv_reduce<<<dim3(NBH), dim3(256), 0, stream>>>(pkv, kvT16);

    // fused middle (MFMA-based)
    res_mfma<<<dim3(NBH, N_SEQ / 128), dim3(256), 0, stream>>>(Qb, Rb, kvT16, km, vm, sin_t, cos_t);

    // output projection (fp32 out)
    gemm_mfma<0, float><<<gg, dim3(256), 0, stream>>>(Rb, wob, bo, out, M_ROWS, C_DIM, C_DIM);
}

// Round 5
// 238.681 us; speedup vs baseline: 5.6115x; 1.0954x over previous
//
#include <hip/hip_runtime.h>
#include <math.h>

// Shapes fixed by setup_inputs: B=4, N=4096 (=64*64), C=768, h=12, d=64
#define B_SZ   4
#define N_SEQ  4096
#define C_DIM  768
#define NH     12
#define HD     64
#define NBH    (B_SZ*NH)
#define SCALE  0.125f
#define M_ROWS (B_SZ*N_SEQ)

typedef unsigned short u16;
typedef short s16x8 __attribute__((ext_vector_type(8)));   // 8 f16 = 4 VGPRs
typedef float f32x4 __attribute__((ext_vector_type(4)));
typedef u16 u16x8 __attribute__((ext_vector_type(8)));

__device__ __forceinline__ u16 f2h(float f) { _Float16 h = (_Float16)f; return __builtin_bit_cast(u16, h); }  // RTN
__device__ __forceinline__ float h2f(u16 u) { return (float)__builtin_bit_cast(_Float16, u); }

__device__ __forceinline__ s16x8 pack_h8(f32x4 x, f32x4 y) {   // RTN pack
    s16x8 o;
    #pragma unroll
    for (int i = 0; i < 4; ++i) { o[i] = (short)f2h(x[i]); o[i+4] = (short)f2h(y[i]); }
    return o;
}

typedef const __attribute__((address_space(1))) void GLBV;
typedef __attribute__((address_space(3))) void LDSV;
#define GLDS(g, l) __builtin_amdgcn_global_load_lds((GLBV*)(g), (LDSV*)(l), 16, 0, 0)

// ---------------- fp32 -> f16 weight convert ----------------
__global__ __launch_bounds__(256)
void cvt_w(const float* __restrict__ w0, const float* __restrict__ w1,
           const float* __restrict__ w2, const float* __restrict__ w3,
           u16* __restrict__ o0, u16* __restrict__ o1, u16* __restrict__ o2, u16* __restrict__ o3) {
    size_t i = ((size_t)blockIdx.x * 256 + threadIdx.x) * 8;
    const float* srcs[4] = {w0 + i, w1 + i, w2 + i, w3 + i};
    u16* dsts[4] = {o0 + i, o1 + i, o2 + i, o3 + i};
    #pragma unroll
    for (int s = 0; s < 4; ++s) {
        float4 x = *(const float4*)srcs[s];
        float4 y = *(const float4*)(srcs[s] + 4);
        u16x8 o;
        o[0] = f2h(x.x); o[1] = f2h(x.y); o[2] = f2h(x.z); o[3] = f2h(x.w);
        o[4] = f2h(y.x); o[5] = f2h(y.y); o[6] = f2h(y.z); o[7] = f2h(y.w);
        *(u16x8*)dsts[s] = o;
    }
}

// ---------------- rope tables (N_SEQ x 64), fp32 ----------------
__global__ void rope_table_k(const int* __restrict__ dH, const int* __restrict__ dW,
                             float* __restrict__ sin_t, float* __restrict__ cos_t) {
    int idx = blockIdx.x * 256 + threadIdx.x;
    if (idx >= N_SEQ * HD) return;
    int n = idx >> 6, j = idx & 63;
    int Wd = dW[0];
    int hh = n / Wd, ww = n % Wd;
    int jj = j & 31;
    float pos = (j < 32) ? (float)hh : (float)ww;
    float freq = powf(10000.0f, -((float)(jj >> 1) / 15.0f));
    float th = pos * freq;
    sin_t[idx] = sinf(th);
    cos_t[idx] = cosf(th);
}

// ---------------- fused cvt + f16 MFMA GEMM: C = A_f32[M][768] @ Bw_f16[768][768]^T + bias ----------------
// A staged fp32 via global_load_lds, source XOR-swizzled (rule 21); B f16 likewise (4-way max).
template<int ACT>
__global__ __launch_bounds__(256)
void gemm_f32a(const float* __restrict__ A, const u16* __restrict__ Bw,
               const float* __restrict__ bias, u16* __restrict__ Cc) {
    constexpr int K = C_DIM, Nn = C_DIM;
    __shared__ __align__(16) float As[128 * 32];   // 16KB
    __shared__ __align__(16) u16  Bs[128 * 32];    // 8KB
    const int t = threadIdx.x;
    const int lane = t & 63, w = t >> 6;
    const int wr = w >> 1, wc = w & 1;
    const int bid = blockIdx.x;
    const int wg = (bid & 7) * 96 + (bid >> 3);    // XCD-chunked, 768%8==0 bijective
    const int bx = wg % 6, by = wg / 6;
    const int m0 = by * 128, n0 = bx * 128;

    // A: 4 rounds x 32 rows x 128B; source col XOR ((row&3)<<5)B -> LDS linear
    const int arow = w * 8 + (lane >> 3);
    const int acolb = ((lane & 7) * 16) ^ (((lane >> 3) & 3) << 5);
    const char* gA = (const char*)(A + (size_t)(m0 + arow) * K) + acolb;
    float* lA = &As[w * 8 * 32];
    // B: 2 rounds x 64 rows x 64B; source col XOR ((row&3)*16)B
    const int brow = w * 16 + (lane >> 2);
    const int bcol = ((lane & 3) * 8) ^ (((lane >> 2) & 3) << 3);
    const u16* gB0 = Bw + (size_t)(n0 + brow) * K + bcol;
    const u16* gB1 = gB0 + (size_t)64 * K;
    u16* lB0 = &Bs[w * 512];
    u16* lB1 = &Bs[2048 + w * 512];

    f32x4 acc[4][4] = {};
    const int ra = lane & 15, kg = (lane >> 4) * 8;
    const int aswz = kg ^ ((ra & 3) << 3);   // float idx
    const int bswz = kg ^ ((ra & 3) << 3);   // u16 idx

    for (int k0 = 0; k0 < K; k0 += 32) {
        __syncthreads();
        #pragma unroll
        for (int r = 0; r < 4; ++r)
            GLDS(gA + (size_t)r * 32 * K * 4, lA + r * 32 * 32);
        GLDS(gB0, lB0); GLDS(gB1, lB1);
        gA += 128; gB0 += 32; gB1 += 32;
        __syncthreads();
        s16x8 av[4], bv[4];
        #pragma unroll
        for (int i = 0; i < 4; ++i) {
            const float* ap = &As[(wr * 64 + i * 16 + ra) * 32 + aswz];
            av[i] = pack_h8(*(const f32x4*)ap, *(const f32x4*)(ap + 4));
        }
        #pragma unroll
        for (int j = 0; j < 4; ++j)
            bv[j] = *(const s16x8*)&Bs[(wc * 64 + j * 16 + ra) * 32 + bswz];
        #pragma unroll
        for (int i = 0; i < 4; ++i)
            #pragma unroll
            for (int j = 0; j < 4; ++j)
                asm("v_mfma_f32_16x16x32_f16 %0, %1, %2, %0"
                    : "+v"(acc[i][j]) : "v"(av[i]), "v"(bv[j]));
    }

    const int cr4 = (lane >> 4) * 4, cc = lane & 15;
    #pragma unroll
    for (int j = 0; j < 4; ++j) {
        const int col = n0 + wc * 64 + j * 16 + cc;
        const float bj = bias[col];
        #pragma unroll
        for (int i = 0; i < 4; ++i) {
            const int row = m0 + wr * 64 + i * 16 + cr4;
            #pragma unroll
            for (int r = 0; r < 4; ++r) {
                float v = acc[i][j][r] + bj;
                if (ACT) v = (v > 0.f) ? (v + 1.f) : __expf(v);   // elu+1
                Cc[(size_t)(row + r) * Nn + col] = f2h(v);
            }
        }
    }
}

// ---------------- Q-projection: GEMM + elu+1 + fp32 z + fp32 rope -> qr(f16), z(f32) ----------------
__global__ __launch_bounds__(256)
void gemm_q(const float* __restrict__ A, const u16* __restrict__ Bw,
            const float* __restrict__ bias, const float* __restrict__ km,
            const float* __restrict__ sin_t, const float* __restrict__ cos_t,
            u16* __restrict__ Qr, float* __restrict__ zbuf) {
    constexpr int K = C_DIM, Nn = C_DIM;
    __shared__ __align__(16) float As[128 * 32];
    __shared__ __align__(16) u16  Bs[128 * 32];
    const int t = threadIdx.x;
    const int lane = t & 63, w = t >> 6;
    const int wr = w >> 1, wc = w & 1;
    const int bid = blockIdx.x;
    const int wg = (bid & 7) * 96 + (bid >> 3);
    const int bx = wg % 6, by = wg / 6;
    const int m0 = by * 128, n0 = bx * 128;

    const int arow = w * 8 + (lane >> 3);
    const int acolb = ((lane & 7) * 16) ^ (((lane >> 3) & 3) << 5);
    const char* gA = (const char*)(A + (size_t)(m0 + arow) * K) + acolb;
    float* lA = &As[w * 8 * 32];
    const int brow = w * 16 + (lane >> 2);
    const int bcol = ((lane & 3) * 8) ^ (((lane >> 2) & 3) << 3);
    const u16* gB0 = Bw + (size_t)(n0 + brow) * K + bcol;
    const u16* gB1 = gB0 + (size_t)64 * K;
    u16* lB0 = &Bs[w * 512];
    u16* lB1 = &Bs[2048 + w * 512];

    f32x4 acc[4][4] = {};
    const int ra = lane & 15, kg = (lane >> 4) * 8;
    const int swz = kg ^ ((ra & 3) << 3);

    for (int k0 = 0; k0 < K; k0 += 32) {
        __syncthreads();
        #pragma unroll
        for (int r = 0; r < 4; ++r)
            GLDS(gA + (size_t)r * 32 * K * 4, lA + r * 32 * 32);
        GLDS(gB0, lB0); GLDS(gB1, lB1);
        gA += 128; gB0 += 32; gB1 += 32;
        __syncthreads();
        s16x8 av[4], bv[4];
        #pragma unroll
        for (int i = 0; i < 4; ++i) {
            const float* ap = &As[(wr * 64 + i * 16 + ra) * 32 + swz];
            av[i] = pack_h8(*(const f32x4*)ap, *(const f32x4*)(ap + 4));
        }
        #pragma unroll
        for (int j = 0; j < 4; ++j)
            bv[j] = *(const s16x8*)&Bs[(wc * 64 + j * 16 + ra) * 32 + swz];
        #pragma unroll
        for (int i = 0; i < 4; ++i)
            #pragma unroll
            for (int j = 0; j < 4; ++j)
                asm("v_mfma_f32_16x16x32_f16 %0, %1, %2, %0"
                    : "+v"(acc[i][j]) : "v"(av[i]), "v"(bv[j]));
    }

    // epilogue: elu+1 (fp32), z = scale * q . km (exact, 16-lane reduce), rope (fp32), store f16
    const int cr4 = (lane >> 4) * 4, cc = lane & 15;
    const int b = m0 >> 12;                       // m0 / 4096
    const int hh0 = n0 >> 6;                      // first head in tile
    const int h = hh0 + wc;
    float kmv[4];
    #pragma unroll
    for (int j = 0; j < 4; ++j) kmv[j] = km[(b * NH + h) * HD + j * 16 + cc];

    #pragma unroll
    for (int i = 0; i < 4; ++i) {
        #pragma unroll
        for (int r = 0; r < 4; ++r) {
            const int row = m0 + wr * 64 + i * 16 + cr4 + r;   // global row
            const int n = row & (N_SEQ - 1);
            float q[4], zp = 0.f;
            #pragma unroll
            for (int j = 0; j < 4; ++j) {
                float v = acc[i][j][r] + bias[n0 + wc * 64 + j * 16 + cc];
                v = (v > 0.f) ? (v + 1.f) : __expf(v);          // elu+1
                q[j] = v;
                zp += v * kmv[j];
            }
            zp += __shfl_xor(zp, 1); zp += __shfl_xor(zp, 2);
            zp += __shfl_xor(zp, 4); zp += __shfl_xor(zp, 8);
            if (cc == 0) zbuf[((size_t)(b * NH + h)) * N_SEQ + n] = zp * SCALE;
            #pragma unroll
            for (int j = 0; j < 4; ++j) {
                const int d = j * 16 + cc;
                const float p = __shfl_xor(q[j], 1);
                const float rot = (d & 1) ? p : -p;
                const size_t toff = (size_t)n * HD + d;
                const float qr = q[j] * cos_t[toff] + rot * sin_t[toff];
                Qr[(size_t)row * Nn + n0 + wc * 64 + d] = f2h(qr);
            }
        }
    }
}

// ---------------- f16-A MFMA GEMM (O-projection): fp32 out ----------------
__global__ __launch_bounds__(256)
void gemm_f16a(const u16* __restrict__ A, const u16* __restrict__ Bw,
               const float* __restrict__ bias, float* __restrict__ Cc) {
    constexpr int K = C_DIM, Nn = C_DIM;
    __shared__ __align__(16) u16 As[4096];
    __shared__ __align__(16) u16 Bs[4096];
    const int t = threadIdx.x;
    const int lane = t & 63, w = t >> 6;
    const int wr = w >> 1, wc = w & 1;
    const int bid = blockIdx.x;
    const int wg = (bid & 7) * 96 + (bid >> 3);
    const int bx = wg % 6, by = wg / 6;
    const int m0 = by * 128, n0 = bx * 128;

    const int r0 = w * 16 + (lane >> 2);
    const int c0 = ((lane & 3) * 8) ^ (((lane >> 2) & 3) << 3);
    const u16* gA0 = A + (size_t)(m0 + r0) * K + c0;
    const u16* gA1 = gA0 + (size_t)64 * K;
    const u16* gB0 = Bw + (size_t)(n0 + r0) * K + c0;
    const u16* gB1 = gB0 + (size_t)64 * K;
    u16* lA0 = &As[w * 512]; u16* lA1 = &As[2048 + w * 512];
    u16* lB0 = &Bs[w * 512]; u16* lB1 = &Bs[2048 + w * 512];

    f32x4 acc[4][4] = {};
    const int ra = lane & 15, kg = (lane >> 4) * 8;
    const int swz = kg ^ ((ra & 3) << 3);
    for (int k0 = 0; k0 < K; k0 += 32) {
        __syncthreads();
        GLDS(gA0, lA0); GLDS(gA1, lA1);
        GLDS(gB0, lB0); GLDS(gB1, lB1);
        gA0 += 32; gA1 += 32; gB0 += 32; gB1 += 32;
        __syncthreads();
        s16x8 av[4], bv[4];
        #pragma unroll
        for (int i = 0; i < 4; ++i)
            av[i] = *(const s16x8*)&As[(wr * 64 + i * 16 + ra) * 32 + swz];
        #pragma unroll
        for (int j = 0; j < 4; ++j)
            bv[j] = *(const s16x8*)&Bs[(wc * 64 + j * 16 + ra) * 32 + swz];
        #pragma unroll
        for (int i = 0; i < 4; ++i)
            #pragma unroll
            for (int j = 0; j < 4; ++j)
                asm("v_mfma_f32_16x16x32_f16 %0, %1, %2, %0"
                    : "+v"(acc[i][j]) : "v"(av[i]), "v"(bv[j]));
    }

    const int cr4 = (lane >> 4) * 4, cc = lane & 15;
    #pragma unroll
    for (int j = 0; j < 4; ++j) {
        const int col = n0 + wc * 64 + j * 16 + cc;
        const float bj = bias[col];
        #pragma unroll
        for (int i = 0; i < 4; ++i) {
            const int row = m0 + wr * 64 + i * 16 + cr4;
            #pragma unroll
            for (int r = 0; r < 4; ++r)
                Cc[(size_t)(row + r) * Nn + col] = acc[i][j][r] + bj;
        }
    }
}

// ---------------- kv partials + column sums (fused), f16 in ----------------
__global__ __launch_bounds__(256)
void kv_partial(const u16* __restrict__ Kb, const u16* __restrict__ Vb,
                const float* __restrict__ sin_t, const float* __restrict__ cos_t,
                float* __restrict__ pkv, float* __restrict__ pk, float* __restrict__ pv) {
    int bh = blockIdx.x, chunk = blockIdx.y;
    int b = bh / NH, h = bh % NH;
    int t = threadIdx.x, tx = t & 15, ty = t >> 4;
    __shared__ float Kt[32][64];
    __shared__ float Vt[32][64];
    float acc[4][4] = {};
    float sk[8] = {}, sv[8] = {};
    int n0 = chunk * 128;
    int lr = t >> 3, lc = (t & 7) * 8;
    for (int nc = 0; nc < 128; nc += 32) {
        int n = n0 + nc + lr;
        size_t off = ((size_t)b * N_SEQ + n) * C_DIM + h * HD + lc;
        size_t toff = (size_t)n * HD + lc;
        u16x8 k8 = *(const u16x8*)&Kb[off];
        u16x8 v8 = *(const u16x8*)&Vb[off];
        float kf[8], vf[8];
        #pragma unroll
        for (int i = 0; i < 8; ++i) {
            kf[i] = h2f(k8[i]); vf[i] = h2f(v8[i]);
            sk[i] += kf[i]; sv[i] += vf[i];
        }
        float4 s1 = *(const float4*)&sin_t[toff];
        float4 s2 = *(const float4*)&sin_t[toff + 4];
        float4 c1 = *(const float4*)&cos_t[toff];
        float4 c2 = *(const float4*)&cos_t[toff + 4];
        float sn[8] = {s1.x, s1.y, s1.z, s1.w, s2.x, s2.y, s2.z, s2.w};
        float cs[8] = {c1.x, c1.y, c1.z, c1.w, c2.x, c2.y, c2.z, c2.w};
        float kr[8];
        #pragma unroll
        for (int e = 0; e < 8; e += 2) {
            kr[e]   = kf[e] * cs[e]     - kf[e+1] * sn[e];
            kr[e+1] = kf[e+1] * cs[e+1] + kf[e]   * sn[e+1];
        }
        __syncthreads();
        #pragma unroll
        for (int i = 0; i < 8; ++i) { Kt[lr][lc + i] = kr[i]; Vt[lr][lc + i] = vf[i]; }
        __syncthreads();
        #pragma unroll
        for (int nn = 0; nn < 32; ++nn) {
            float a[4], bb[4];
            #pragma unroll
            for (int i = 0; i < 4; ++i) a[i] = Kt[nn][ty * 4 + i];
            #pragma unroll
            for (int j = 0; j < 4; ++j) bb[j] = Vt[nn][tx * 4 + j];
            #pragma unroll
            for (int i = 0; i < 4; ++i)
                #pragma unroll
                for (int j = 0; j < 4; ++j)
                    acc[i][j] += a[i] * bb[j];
        }
    }
    size_t obase = ((size_t)bh * 32 + chunk) * 4096;
    #pragma unroll
    for (int i = 0; i < 4; ++i)
        #pragma unroll
        for (int j = 0; j < 4; ++j)
            pkv[obase + (ty * 4 + i) * 64 + (tx * 4 + j)] = acc[i][j];
    __syncthreads();
    #pragma unroll
    for (int i = 0; i < 8; ++i) { Kt[lr][lc + i] = sk[i]; Vt[lr][lc + i] = sv[i]; }
    __syncthreads();
    if (t < 64) {
        float s1 = 0.f, s2 = 0.f;
        #pragma unroll
        for (int r = 0; r < 32; ++r) { s1 += Kt[r][t]; s2 += Vt[r][t]; }
        pk[((size_t)bh * 32 + chunk) * 64 + t] = s1;
        pv[((size_t)bh * 32 + chunk) * 64 + t] = s2;
    }
}

// ---------------- merged reduce: kvT (f16 hi/lo, transposed [e][d]) + km/vm ----------------
__global__ __launch_bounds__(256)
void kvred(const float* __restrict__ pkv, const float* __restrict__ pk, const float* __restrict__ pv,
           u16* __restrict__ kvT, float* __restrict__ km, float* __restrict__ vm) {
    int bh = blockIdx.x, t = threadIdx.x;
    int u = blockIdx.y * 256 + t;
    float s = 0.f;
    for (int c = 0; c < 32; ++c) s += pkv[((size_t)bh * 32 + c) * 4096 + u];
    s *= (SCALE / N_SEQ);
    int d = u >> 6, e = u & 63;
    u16 hi = f2h(s);
    u16 lo = f2h(s - h2f(hi));
    kvT[(size_t)bh * 8192 + e * 64 + d] = hi;
    kvT[(size_t)bh * 8192 + 4096 + e * 64 + d] = lo;
    if (blockIdx.y == 0 && t < 128) {
        int which = t >> 6, lane = t & 63;
        const float* src = which ? pv : pk;
        float s2 = 0.f;
        for (int c = 0; c < 32; ++c) s2 += src[((size_t)bh * 32 + c) * 64 + lane];
        (which ? vm : km)[bh * 64 + lane] = s2 * (1.0f / N_SEQ);
    }
}

// ---------------- res: MFMA(qr @ kv_hi + qr @ kv_lo) + rescale; in-place on Qr ----------------
#define LDQ 72
__global__ __launch_bounds__(256)
void res_mfma(u16* __restrict__ Qr,
              const u16* __restrict__ kvT,
              const float* __restrict__ vmean, const float* __restrict__ zbuf) {
    __shared__ __align__(16) u16 qs[128 * LDQ];
    __shared__ __align__(16) u16 kvs[2][64 * LDQ];
    __shared__ float zs[128];
    __shared__ float vms[64];
    const int bh = blockIdx.x;
    const int b = bh / NH, h = bh % NH;
    const int n0 = blockIdx.y * 128;
    const int t = threadIdx.x;
    const int lane = t & 63, w = t >> 6;

    {   // stage kv^T hi/lo
        const int r = t >> 2, c = (t & 3) * 16;
        #pragma unroll
        for (int p = 0; p < 2; ++p) {
            size_t g = (size_t)bh * 8192 + p * 4096 + r * 64 + c;
            *(u16x8*)&kvs[p][r * LDQ + c]     = *(const u16x8*)&kvT[g];
            *(u16x8*)&kvs[p][r * LDQ + c + 8] = *(const u16x8*)&kvT[g + 8];
        }
    }
    if (t < 64) vms[t] = vmean[bh * 64 + t];
    else if (t < 192) zs[t - 64] = zbuf[(size_t)bh * N_SEQ + n0 + (t - 64)];
    // stage qr
    #pragma unroll
    for (int ri = 0; ri < 4; ++ri) {
        const int row = ri * 32 + (t >> 3);
        const int c = (t & 7) * 8;
        size_t off = ((size_t)b * N_SEQ + n0 + row) * C_DIM + (size_t)h * HD + c;
        *(u16x8*)&qs[row * LDQ + c] = *(const u16x8*)&Qr[off];
    }
    __syncthreads();

    f32x4 acc[2][4] = {};
    const int ra = lane & 15, kg = (lane >> 4) * 8;
    #pragma unroll
    for (int p = 0; p < 2; ++p) {
        #pragma unroll
        for (int hh = 0; hh < 2; ++hh) {
            s16x8 bv[4];
            #pragma unroll
            for (int j = 0; j < 4; ++j)
                bv[j] = *(const s16x8*)&kvs[p][(j * 16 + ra) * LDQ + hh * 32 + kg];
            #pragma unroll
            for (int i = 0; i < 2; ++i) {
                s16x8 av = *(const s16x8*)&qs[(w * 32 + i * 16 + ra) * LDQ + hh * 32 + kg];
                #pragma unroll
                for (int j = 0; j < 4; ++j)
                    asm("v_mfma_f32_16x16x32_f16 %0, %1, %2, %0"
                        : "+v"(acc[i][j]) : "v"(av), "v"(bv[j]));
            }
        }
    }

    const int cr4 = (lane >> 4) * 4, cc = lane & 15;
    #pragma unroll
    for (int i = 0; i < 2; ++i) {
        #pragma unroll
        for (int j = 0; j < 4; ++j) {
            const int col = j * 16 + cc;
            const float vmc = vms[col];
            #pragma unroll
            for (int r = 0; r < 4; ++r) {
                const int row = w * 32 + i * 16 + cr4 + r;
                const float z = zs[row];
                const float v = acc[i][j][r] * (1.0f + 1.0f / (z + 1e-6f)) - z * vmc;
                Qr[((size_t)b * N_SEQ + n0 + row) * C_DIM + (size_t)h * HD + col] = f2h(v);
            }
        }
    }
}

extern "C" void kernel_launch(void* const* d_in, const int* in_sizes, int n_in,
                              void* d_out, int out_size, void* d_ws, size_t ws_size,
                              hipStream_t stream) {
    const float* query = (const float*)d_in[0];
    const float* key   = (const float*)d_in[1];
    const float* value = (const float*)d_in[2];
    const float* Wq = (const float*)d_in[3];
    const float* bq = (const float*)d_in[4];
    const float* Wk = (const float*)d_in[5];
    const float* bk = (const float*)d_in[6];
    const float* Wv = (const float*)d_in[7];
    const float* bv = (const float*)d_in[8];
    const float* Wo = (const float*)d_in[9];
    const float* bo = (const float*)d_in[10];
    const int* dH = (const int*)d_in[11];
    const int* dW = (const int*)d_in[12];
    float* out = (float*)d_out;

    const size_t mc = (size_t)M_ROWS * C_DIM;   // 12,582,912
    const size_t wsz = (size_t)C_DIM * C_DIM;   // 589,824

    // f16 buffers
    u16* ws16 = (u16*)d_ws;
    u16* Qr  = ws16;             // mc (qr, then res in-place)
    u16* Kb  = Qr + mc;          // mc
    u16* Vb  = Kb + mc;          // mc
    u16* wqb = Vb + mc;          // wsz x4
    u16* wkb = wqb + wsz;
    u16* wvb = wkb + wsz;
    u16* wob = wvb + wsz;
    u16* kvT = wob + wsz;        // NBH*8192 (hi/lo)

    // fp32 buffers
    float* wsf = (float*)(kvT + (size_t)NBH * 8192);
    float* sin_t = wsf;                          // 262144
    float* cos_t = sin_t + (size_t)N_SEQ * HD;   // 262144
    float* pk    = cos_t + (size_t)N_SEQ * HD;   // NBH*32*64
    float* pv    = pk + (size_t)NBH * 32 * 64;
    float* km    = pv + (size_t)NBH * 32 * 64;   // NBH*64
    float* vm    = km + NBH * 64;
    float* zbuf  = vm + NBH * 64;                // NBH*4096
    float* pkv   = zbuf + (size_t)NBH * N_SEQ;   // NBH*32*4096 = 25MB

    // weights + tables
    cvt_w<<<dim3(288), dim3(256), 0, stream>>>(Wq, Wk, Wv, Wo, wqb, wkb, wvb, wob);
    rope_table_k<<<dim3(1024), dim3(256), 0, stream>>>(dH, dW, sin_t, cos_t);

    // K, V projections first (fused fp32->f16 cvt + f16 MFMA)
    gemm_f32a<1><<<dim3(768), dim3(256), 0, stream>>>(key,   wkb, bk, Kb);
    gemm_f32a<0><<<dim3(768), dim3(256), 0, stream>>>(value, wvb, bv, Vb);

    // kv partials (+ fused column sums), then merged reduce -> km, vm, kvT
    kv_partial<<<dim3(NBH, 32), dim3(256), 0, stream>>>(Kb, Vb, sin_t, cos_t, pkv, pk, pv);
    kvred<<<dim3(NBH, 16), dim3(256), 0, stream>>>(pkv, pk, pv, kvT, km, vm);

    // Q projection with fused exact-z + rope
    gemm_q<<<dim3(768), dim3(256), 0, stream>>>(query, wqb, bq, km, sin_t, cos_t, Qr, zbuf);

    // res (in-place on Qr)
    res_mfma<<<dim3(NBH, N_SEQ / 128), dim3(256), 0, stream>>>(Qr, kvT, vm, zbuf);

    // output projection (fp32 out)
    gemm_f16a<<<dim3(768), dim3(256), 0, stream>>>(Qr, wob, bo, out);
}

// Round 8
// 237.759 us; speedup vs baseline: 5.6333x; 1.0039x over previous
//
#include <hip/hip_runtime.h>
#include <math.h>

// Shapes fixed by setup_inputs: B=4, N=4096 (=64*64), C=768, h=12, d=64
#define B_SZ   4
#define N_SEQ  4096
#define C_DIM  768
#define NH     12
#define HD     64
#define NBH    (B_SZ*NH)
#define SCALE  0.125f
#define M_ROWS (B_SZ*N_SEQ)

typedef unsigned short u16;
typedef short s16x8 __attribute__((ext_vector_type(8)));   // 8 f16 = 4 VGPRs
typedef float f32x4 __attribute__((ext_vector_type(4)));
typedef u16 u16x8 __attribute__((ext_vector_type(8)));

__device__ __forceinline__ u16 f2h(float f) { _Float16 h = (_Float16)f; return __builtin_bit_cast(u16, h); }  // RTN
__device__ __forceinline__ float h2f(u16 u) { return (float)__builtin_bit_cast(_Float16, u); }

__device__ __forceinline__ s16x8 pack_h8(f32x4 x, f32x4 y) {   // RTN pack
    s16x8 o;
    #pragma unroll
    for (int i = 0; i < 4; ++i) { o[i] = (short)f2h(x[i]); o[i+4] = (short)f2h(y[i]); }
    return o;
}

typedef const __attribute__((address_space(1))) void GLBV;
typedef __attribute__((address_space(3))) void LDSV;
#define GLDS(g, l) __builtin_amdgcn_global_load_lds((GLBV*)(g), (LDSV*)(l), 16, 0, 0)

// ---------------- fp32 -> f16 weight convert ----------------
__global__ __launch_bounds__(256)
void cvt_w(const float* __restrict__ w0, const float* __restrict__ w1,
           const float* __restrict__ w2, const float* __restrict__ w3,
           u16* __restrict__ o0, u16* __restrict__ o1, u16* __restrict__ o2, u16* __restrict__ o3) {
    size_t i = ((size_t)blockIdx.x * 256 + threadIdx.x) * 8;
    const float* srcs[4] = {w0 + i, w1 + i, w2 + i, w3 + i};
    u16* dsts[4] = {o0 + i, o1 + i, o2 + i, o3 + i};
    #pragma unroll
    for (int s = 0; s < 4; ++s) {
        float4 x = *(const float4*)srcs[s];
        float4 y = *(const float4*)(srcs[s] + 4);
        u16x8 o;
        o[0] = f2h(x.x); o[1] = f2h(x.y); o[2] = f2h(x.z); o[3] = f2h(x.w);
        o[4] = f2h(y.x); o[5] = f2h(y.y); o[6] = f2h(y.z); o[7] = f2h(y.w);
        *(u16x8*)dsts[s] = o;
    }
}

// ---------------- rope tables (N_SEQ x 64), fp32 ----------------
__global__ void rope_table_k(const int* __restrict__ dH, const int* __restrict__ dW,
                             float* __restrict__ sin_t, float* __restrict__ cos_t) {
    int idx = blockIdx.x * 256 + threadIdx.x;
    if (idx >= N_SEQ * HD) return;
    int n = idx >> 6, j = idx & 63;
    int Wd = dW[0];
    int hh = n / Wd, ww = n % Wd;
    int jj = j & 31;
    float pos = (j < 32) ? (float)hh : (float)ww;
    float freq = powf(10000.0f, -((float)(jj >> 1) / 15.0f));
    float th = pos * freq;
    sin_t[idx] = sinf(th);
    cos_t[idx] = cosf(th);
}

// ---------------- fused cvt + f16 MFMA GEMM: C = A_f32[M][768] @ Bw_f16[768][768]^T + bias ----------------
// A staged fp32 via global_load_lds, source XOR-swizzled (rule 21); B f16 likewise (4-way max).
template<int ACT>
__global__ __launch_bounds__(256)
void gemm_f32a(const float* __restrict__ A, const u16* __restrict__ Bw,
               const float* __restrict__ bias, u16* __restrict__ Cc) {
    constexpr int K = C_DIM, Nn = C_DIM;
    __shared__ __align__(16) float As[128 * 32];   // 16KB
    __shared__ __align__(16) u16  Bs[128 * 32];    // 8KB
    const int t = threadIdx.x;
    const int lane = t & 63, w = t >> 6;
    const int wr = w >> 1, wc = w & 1;
    const int bid = blockIdx.x;
    const int wg = (bid & 7) * 96 + (bid >> 3);    // XCD-chunked, 768%8==0 bijective
    const int bx = wg % 6, by = wg / 6;
    const int m0 = by * 128, n0 = bx * 128;

    // A: 4 rounds x 32 rows x 128B; source col XOR ((row&3)<<5)B -> LDS linear
    const int arow = w * 8 + (lane >> 3);
    const int acolb = ((lane & 7) * 16) ^ (((lane >> 3) & 3) << 5);
    const char* gA = (const char*)(A + (size_t)(m0 + arow) * K) + acolb;
    float* lA = &As[w * 8 * 32];
    // B: 2 rounds x 64 rows x 64B; source col XOR ((row&3)*16)B
    const int brow = w * 16 + (lane >> 2);
    const int bcol = ((lane & 3) * 8) ^ (((lane >> 2) & 3) << 3);
    const u16* gB0 = Bw + (size_t)(n0 + brow) * K + bcol;
    const u16* gB1 = gB0 + (size_t)64 * K;
    u16* lB0 = &Bs[w * 512];
    u16* lB1 = &Bs[2048 + w * 512];

    f32x4 acc[4][4] = {};
    const int ra = lane & 15, kg = (lane >> 4) * 8;
    const int aswz = kg ^ ((ra & 3) << 3);   // float idx
    const int bswz = kg ^ ((ra & 3) << 3);   // u16 idx

    for (int k0 = 0; k0 < K; k0 += 32) {
        __syncthreads();
        #pragma unroll
        for (int r = 0; r < 4; ++r)
            GLDS(gA + (size_t)r * 32 * K * 4, lA + r * 32 * 32);
        GLDS(gB0, lB0); GLDS(gB1, lB1);
        gA += 128; gB0 += 32; gB1 += 32;
        __syncthreads();
        s16x8 av[4], bv[4];
        #pragma unroll
        for (int i = 0; i < 4; ++i) {
            const float* ap = &As[(wr * 64 + i * 16 + ra) * 32 + aswz];
            av[i] = pack_h8(*(const f32x4*)ap, *(const f32x4*)(ap + 4));
        }
        #pragma unroll
        for (int j = 0; j < 4; ++j)
            bv[j] = *(const s16x8*)&Bs[(wc * 64 + j * 16 + ra) * 32 + bswz];
        #pragma unroll
        for (int i = 0; i < 4; ++i)
            #pragma unroll
            for (int j = 0; j < 4; ++j)
                asm("v_mfma_f32_16x16x32_f16 %0, %1, %2, %0"
                    : "+v"(acc[i][j]) : "v"(av[i]), "v"(bv[j]));
    }

    const int cr4 = (lane >> 4) * 4, cc = lane & 15;
    #pragma unroll
    for (int j = 0; j < 4; ++j) {
        const int col = n0 + wc * 64 + j * 16 + cc;
        const float bj = bias[col];
        #pragma unroll
        for (int i = 0; i < 4; ++i) {
            const int row = m0 + wr * 64 + i * 16 + cr4;
            #pragma unroll
            for (int r = 0; r < 4; ++r) {
                float v = acc[i][j][r] + bj;
                if (ACT) v = (v > 0.f) ? (v + 1.f) : __expf(v);   // elu+1
                Cc[(size_t)(row + r) * Nn + col] = f2h(v);
            }
        }
    }
}

// ---------------- Q-projection: GEMM + elu+1 + fp32 z + fp32 rope -> qr(f16), z(f32) ----------------
__global__ __launch_bounds__(256)
void gemm_q(const float* __restrict__ A, const u16* __restrict__ Bw,
            const float* __restrict__ bias, const float* __restrict__ km,
            const float* __restrict__ sin_t, const float* __restrict__ cos_t,
            u16* __restrict__ Qr, float* __restrict__ zbuf) {
    constexpr int K = C_DIM, Nn = C_DIM;
    __shared__ __align__(16) float As[128 * 32];
    __shared__ __align__(16) u16  Bs[128 * 32];
    const int t = threadIdx.x;
    const int lane = t & 63, w = t >> 6;
    const int wr = w >> 1, wc = w & 1;
    const int bid = blockIdx.x;
    const int wg = (bid & 7) * 96 + (bid >> 3);
    const int bx = wg % 6, by = wg / 6;
    const int m0 = by * 128, n0 = bx * 128;

    const int arow = w * 8 + (lane >> 3);
    const int acolb = ((lane & 7) * 16) ^ (((lane >> 3) & 3) << 5);
    const char* gA = (const char*)(A + (size_t)(m0 + arow) * K) + acolb;
    float* lA = &As[w * 8 * 32];
    const int brow = w * 16 + (lane >> 2);
    const int bcol = ((lane & 3) * 8) ^ (((lane >> 2) & 3) << 3);
    const u16* gB0 = Bw + (size_t)(n0 + brow) * K + bcol;
    const u16* gB1 = gB0 + (size_t)64 * K;
    u16* lB0 = &Bs[w * 512];
    u16* lB1 = &Bs[2048 + w * 512];

    f32x4 acc[4][4] = {};
    const int ra = lane & 15, kg = (lane >> 4) * 8;
    const int swz = kg ^ ((ra & 3) << 3);

    for (int k0 = 0; k0 < K; k0 += 32) {
        __syncthreads();
        #pragma unroll
        for (int r = 0; r < 4; ++r)
            GLDS(gA + (size_t)r * 32 * K * 4, lA + r * 32 * 32);
        GLDS(gB0, lB0); GLDS(gB1, lB1);
        gA += 128; gB0 += 32; gB1 += 32;
        __syncthreads();
        s16x8 av[4], bv[4];
        #pragma unroll
        for (int i = 0; i < 4; ++i) {
            const float* ap = &As[(wr * 64 + i * 16 + ra) * 32 + swz];
            av[i] = pack_h8(*(const f32x4*)ap, *(const f32x4*)(ap + 4));
        }
        #pragma unroll
        for (int j = 0; j < 4; ++j)
            bv[j] = *(const s16x8*)&Bs[(wc * 64 + j * 16 + ra) * 32 + swz];
        #pragma unroll
        for (int i = 0; i < 4; ++i)
            #pragma unroll
            for (int j = 0; j < 4; ++j)
                asm("v_mfma_f32_16x16x32_f16 %0, %1, %2, %0"
                    : "+v"(acc[i][j]) : "v"(av[i]), "v"(bv[j]));
    }

    // epilogue: elu+1 (fp32), z = scale * q . km (exact, 16-lane reduce), rope (fp32), store f16
    const int cr4 = (lane >> 4) * 4, cc = lane & 15;
    const int b = m0 >> 12;                       // m0 / 4096
    const int hh0 = n0 >> 6;                      // first head in tile
    const int h = hh0 + wc;
    float kmv[4];
    #pragma unroll
    for (int j = 0; j < 4; ++j) kmv[j] = km[(b * NH + h) * HD + j * 16 + cc];

    #pragma unroll
    for (int i = 0; i < 4; ++i) {
        #pragma unroll
        for (int r = 0; r < 4; ++r) {
            const int row = m0 + wr * 64 + i * 16 + cr4 + r;   // global row
            const int n = row & (N_SEQ - 1);
            float q[4], zp = 0.f;
            #pragma unroll
            for (int j = 0; j < 4; ++j) {
                float v = acc[i][j][r] + bias[n0 + wc * 64 + j * 16 + cc];
                v = (v > 0.f) ? (v + 1.f) : __expf(v);          // elu+1
                q[j] = v;
                zp += v * kmv[j];
            }
            zp += __shfl_xor(zp, 1); zp += __shfl_xor(zp, 2);
            zp += __shfl_xor(zp, 4); zp += __shfl_xor(zp, 8);
            if (cc == 0) zbuf[((size_t)(b * NH + h)) * N_SEQ + n] = zp * SCALE;
            #pragma unroll
            for (int j = 0; j < 4; ++j) {
                const int d = j * 16 + cc;
                const float p = __shfl_xor(q[j], 1);
                const float rot = (d & 1) ? p : -p;
                const size_t toff = (size_t)n * HD + d;
                const float qr = q[j] * cos_t[toff] + rot * sin_t[toff];
                Qr[(size_t)row * Nn + n0 + wc * 64 + d] = f2h(qr);
            }
        }
    }
}

// ---------------- f16-A MFMA GEMM (O-projection): fp32 out ----------------
__global__ __launch_bounds__(256)
void gemm_f16a(const u16* __restrict__ A, const u16* __restrict__ Bw,
               const float* __restrict__ bias, float* __restrict__ Cc) {
    constexpr int K = C_DIM, Nn = C_DIM;
    __shared__ __align__(16) u16 As[4096];
    __shared__ __align__(16) u16 Bs[4096];
    const int t = threadIdx.x;
    const int lane = t & 63, w = t >> 6;
    const int wr = w >> 1, wc = w & 1;
    const int bid = blockIdx.x;
    const int wg = (bid & 7) * 96 + (bid >> 3);
    const int bx = wg % 6, by = wg / 6;
    const int m0 = by * 128, n0 = bx * 128;

    const int r0 = w * 16 + (lane >> 2);
    const int c0 = ((lane & 3) * 8) ^ (((lane >> 2) & 3) << 3);
    const u16* gA0 = A + (size_t)(m0 + r0) * K + c0;
    const u16* gA1 = gA0 + (size_t)64 * K;
    const u16* gB0 = Bw + (size_t)(n0 + r0) * K + c0;
    const u16* gB1 = gB0 + (size_t)64 * K;
    u16* lA0 = &As[w * 512]; u16* lA1 = &As[2048 + w * 512];
    u16* lB0 = &Bs[w * 512]; u16* lB1 = &Bs[2048 + w * 512];

    f32x4 acc[4][4] = {};
    const int ra = lane & 15, kg = (lane >> 4) * 8;
    const int swz = kg ^ ((ra & 3) << 3);
    for (int k0 = 0; k0 < K; k0 += 32) {
        __syncthreads();
        GLDS(gA0, lA0); GLDS(gA1, lA1);
        GLDS(gB0, lB0); GLDS(gB1, lB1);
        gA0 += 32; gA1 += 32; gB0 += 32; gB1 += 32;
        __syncthreads();
        s16x8 av[4], bv[4];
        #pragma unroll
        for (int i = 0; i < 4; ++i)
            av[i] = *(const s16x8*)&As[(wr * 64 + i * 16 + ra) * 32 + swz];
        #pragma unroll
        for (int j = 0; j < 4; ++j)
            bv[j] = *(const s16x8*)&Bs[(wc * 64 + j * 16 + ra) * 32 + swz];
        #pragma unroll
        for (int i = 0; i < 4; ++i)
            #pragma unroll
            for (int j = 0; j < 4; ++j)
                asm("v_mfma_f32_16x16x32_f16 %0, %1, %2, %0"
                    : "+v"(acc[i][j]) : "v"(av[i]), "v"(bv[j]));
    }

    const int cr4 = (lane >> 4) * 4, cc = lane & 15;
    #pragma unroll
    for (int j = 0; j < 4; ++j) {
        const int col = n0 + wc * 64 + j * 16 + cc;
        const float bj = bias[col];
        #pragma unroll
        for (int i = 0; i < 4; ++i) {
            const int row = m0 + wr * 64 + i * 16 + cr4;
            #pragma unroll
            for (int r = 0; r < 4; ++r)
                Cc[(size_t)(row + r) * Nn + col] = acc[i][j][r] + bj;
        }
    }
}

// ---------------- kv partials + column sums (fused), f16 in ----------------
__global__ __launch_bounds__(256)
void kv_partial(const u16* __restrict__ Kb, const u16* __restrict__ Vb,
                const float* __restrict__ sin_t, const float* __restrict__ cos_t,
                float* __restrict__ pkv, float* __restrict__ pk, float* __restrict__ pv) {
    int bh = blockIdx.x, chunk = blockIdx.y;
    int b = bh / NH, h = bh % NH;
    int t = threadIdx.x, tx = t & 15, ty = t >> 4;
    __shared__ float Kt[32][64];
    __shared__ float Vt[32][64];
    float acc[4][4] = {};
    float sk[8] = {}, sv[8] = {};
    int n0 = chunk * 128;
    int lr = t >> 3, lc = (t & 7) * 8;
    for (int nc = 0; nc < 128; nc += 32) {
        int n = n0 + nc + lr;
        size_t off = ((size_t)b * N_SEQ + n) * C_DIM + h * HD + lc;
        size_t toff = (size_t)n * HD + lc;
        u16x8 k8 = *(const u16x8*)&Kb[off];
        u16x8 v8 = *(const u16x8*)&Vb[off];
        float kf[8], vf[8];
        #pragma unroll
        for (int i = 0; i < 8; ++i) {
            kf[i] = h2f(k8[i]); vf[i] = h2f(v8[i]);
            sk[i] += kf[i]; sv[i] += vf[i];
        }
        float4 s1 = *(const float4*)&sin_t[toff];
        float4 s2 = *(const float4*)&sin_t[toff + 4];
        float4 c1 = *(const float4*)&cos_t[toff];
        float4 c2 = *(const float4*)&cos_t[toff + 4];
        float sn[8] = {s1.x, s1.y, s1.z, s1.w, s2.x, s2.y, s2.z, s2.w};
        float cs[8] = {c1.x, c1.y, c1.z, c1.w, c2.x, c2.y, c2.z, c2.w};
        float kr[8];
        #pragma unroll
        for (int e = 0; e < 8; e += 2) {
            kr[e]   = kf[e] * cs[e]     - kf[e+1] * sn[e];
            kr[e+1] = kf[e+1] * cs[e+1] + kf[e]   * sn[e+1];
        }
        __syncthreads();
        #pragma unroll
        for (int i = 0; i < 8; ++i) { Kt[lr][lc + i] = kr[i]; Vt[lr][lc + i] = vf[i]; }
        __syncthreads();
        #pragma unroll
        for (int nn = 0; nn < 32; ++nn) {
            float a[4], bb[4];
            #pragma unroll
            for (int i = 0; i < 4; ++i) a[i] = Kt[nn][ty * 4 + i];
            #pragma unroll
            for (int j = 0; j < 4; ++j) bb[j] = Vt[nn][tx * 4 + j];
            #pragma unroll
            for (int i = 0; i < 4; ++i)
                #pragma unroll
                for (int j = 0; j < 4; ++j)
                    acc[i][j] += a[i] * bb[j];
        }
    }
    size_t obase = ((size_t)bh * 32 + chunk) * 4096;
    #pragma unroll
    for (int i = 0; i < 4; ++i)
        #pragma unroll
        for (int j = 0; j < 4; ++j)
            pkv[obase + (ty * 4 + i) * 64 + (tx * 4 + j)] = acc[i][j];
    __syncthreads();
    #pragma unroll
    for (int i = 0; i < 8; ++i) { Kt[lr][lc + i] = sk[i]; Vt[lr][lc + i] = sv[i]; }
    __syncthreads();
    if (t < 64) {
        float s1 = 0.f, s2 = 0.f;
        #pragma unroll
        for (int r = 0; r < 32; ++r) { s1 += Kt[r][t]; s2 += Vt[r][t]; }
        pk[((size_t)bh * 32 + chunk) * 64 + t] = s1;
        pv[((size_t)bh * 32 + chunk) * 64 + t] = s2;
    }
}

// ---------------- merged reduce: kvT (f16 hi/lo, transposed [e][d]) + km/vm ----------------
__global__ __launch_bounds__(256)
void kvred(const float* __restrict__ pkv, const float* __restrict__ pk, const float* __restrict__ pv,
           u16* __restrict__ kvT, float* __restrict__ km, float* __restrict__ vm) {
    int bh = blockIdx.x, t = threadIdx.x;
    int u = blockIdx.y * 256 + t;
    float s = 0.f;
    for (int c = 0; c < 32; ++c) s += pkv[((size_t)bh * 32 + c) * 4096 + u];
    s *= (SCALE / N_SEQ);
    int d = u >> 6, e = u & 63;
    u16 hi = f2h(s);
    u16 lo = f2h(s - h2f(hi));
    kvT[(size_t)bh * 8192 + e * 64 + d] = hi;
    kvT[(size_t)bh * 8192 + 4096 + e * 64 + d] = lo;
    if (blockIdx.y == 0 && t < 128) {
        int which = t >> 6, lane = t & 63;
        const float* src = which ? pv : pk;
        float s2 = 0.f;
        for (int c = 0; c < 32; ++c) s2 += src[((size_t)bh * 32 + c) * 64 + lane];
        (which ? vm : km)[bh * 64 + lane] = s2 * (1.0f / N_SEQ);
    }
}

// ---------------- res: MFMA(qr @ kv_hi + qr @ kv_lo) + rescale; in-place on Qr ----------------
#define LDQ 72
__global__ __launch_bounds__(256)
void res_mfma(u16* __restrict__ Qr,
              const u16* __restrict__ kvT,
              const float* __restrict__ vmean, const float* __restrict__ zbuf) {
    __shared__ __align__(16) u16 qs[128 * LDQ];
    __shared__ __align__(16) u16 kvs[2][64 * LDQ];
    __shared__ float zs[128];
    __shared__ float vms[64];
    const int bh = blockIdx.x;
    const int b = bh / NH, h = bh % NH;
    const int n0 = blockIdx.y * 128;
    const int t = threadIdx.x;
    const int lane = t & 63, w = t >> 6;

    {   // stage kv^T hi/lo
        const int r = t >> 2, c = (t & 3) * 16;
        #pragma unroll
        for (int p = 0; p < 2; ++p) {
            size_t g = (size_t)bh * 8192 + p * 4096 + r * 64 + c;
            *(u16x8*)&kvs[p][r * LDQ + c]     = *(const u16x8*)&kvT[g];
            *(u16x8*)&kvs[p][r * LDQ + c + 8] = *(const u16x8*)&kvT[g + 8];
        }
    }
    if (t < 64) vms[t] = vmean[bh * 64 + t];
    else if (t < 192) zs[t - 64] = zbuf[(size_t)bh * N_SEQ + n0 + (t - 64)];
    // stage qr
    #pragma unroll
    for (int ri = 0; ri < 4; ++ri) {
        const int row = ri * 32 + (t >> 3);
        const int c = (t & 7) * 8;
        size_t off = ((size_t)b * N_SEQ + n0 + row) * C_DIM + (size_t)h * HD + c;
        *(u16x8*)&qs[row * LDQ + c] = *(const u16x8*)&Qr[off];
    }
    __syncthreads();

    f32x4 acc[2][4] = {};
    const int ra = lane & 15, kg = (lane >> 4) * 8;
    #pragma unroll
    for (int p = 0; p < 2; ++p) {
        #pragma unroll
        for (int hh = 0; hh < 2; ++hh) {
            s16x8 bv4[4];
            #pragma unroll
            for (int j = 0; j < 4; ++j)
                bv4[j] = *(const s16x8*)&kvs[p][(j * 16 + ra) * LDQ + hh * 32 + kg];
            #pragma unroll
            for (int i = 0; i < 2; ++i) {
                s16x8 av = *(const s16x8*)&qs[(w * 32 + i * 16 + ra) * LDQ + hh * 32 + kg];
                #pragma unroll
                for (int j = 0; j < 4; ++j)
                    asm("v_mfma_f32_16x16x32_f16 %0, %1, %2, %0"
                        : "+v"(acc[i][j]) : "v"(av), "v"(bv4[j]));
            }
        }
    }

    const int cr4 = (lane >> 4) * 4, cc = lane & 15;
    #pragma unroll
    for (int i = 0; i < 2; ++i) {
        #pragma unroll
        for (int j = 0; j < 4; ++j) {
            const int col = j * 16 + cc;
            const float vmc = vms[col];
            #pragma unroll
            for (int r = 0; r < 4; ++r) {
                const int row = w * 32 + i * 16 + cr4 + r;
                const float z = zs[row];
                const float v = acc[i][j][r] * (1.0f + 1.0f / (z + 1e-6f)) - z * vmc;
                Qr[((size_t)b * N_SEQ + n0 + row) * C_DIM + (size_t)h * HD + col] = f2h(v);
            }
        }
    }
}

extern "C" void kernel_launch(void* const* d_in, const int* in_sizes, int n_in,
                              void* d_out, int out_size, void* d_ws, size_t ws_size,
                              hipStream_t stream) {
    const float* query = (const float*)d_in[0];
    const float* key   = (const float*)d_in[1];
    const float* value = (const float*)d_in[2];
    const float* Wq = (const float*)d_in[3];
    const float* bq = (const float*)d_in[4];
    const float* Wk = (const float*)d_in[5];
    const float* bk = (const float*)d_in[6];
    const float* Wv = (const float*)d_in[7];
    const float* bv = (const float*)d_in[8];
    const float* Wo = (const float*)d_in[9];
    const float* bo = (const float*)d_in[10];
    const int* dH = (const int*)d_in[11];
    const int* dW = (const int*)d_in[12];
    float* out = (float*)d_out;

    const size_t mc = (size_t)M_ROWS * C_DIM;   // 12,582,912
    const size_t wsz = (size_t)C_DIM * C_DIM;   // 589,824

    // f16 buffers
    u16* ws16 = (u16*)d_ws;
    u16* Qr  = ws16;             // mc (qr, then res in-place)
    u16* Kb  = Qr + mc;          // mc
    u16* Vb  = Kb + mc;          // mc
    u16* wqb = Vb + mc;          // wsz x4
    u16* wkb = wqb + wsz;
    u16* wvb = wkb + wsz;
    u16* wob = wvb + wsz;
    u16* kvT = wob + wsz;        // NBH*8192 (hi/lo)

    // fp32 buffers
    float* wsf = (float*)(kvT + (size_t)NBH * 8192);
    float* sin_t = wsf;                          // 262144
    float* cos_t = sin_t + (size_t)N_SEQ * HD;   // 262144
    float* pk    = cos_t + (size_t)N_SEQ * HD;   // NBH*32*64
    float* pv    = pk + (size_t)NBH * 32 * 64;
    float* km    = pv + (size_t)NBH * 32 * 64;   // NBH*64
    float* vm    = km + NBH * 64;
    float* zbuf  = vm + NBH * 64;                // NBH*4096
    float* pkv   = zbuf + (size_t)NBH * N_SEQ;   // NBH*32*4096 = 25MB

    // weights + tables
    cvt_w<<<dim3(288), dim3(256), 0, stream>>>(Wq, Wk, Wv, Wo, wqb, wkb, wvb, wob);
    rope_table_k<<<dim3(1024), dim3(256), 0, stream>>>(dH, dW, sin_t, cos_t);

    // K, V projections first (fused fp32->f16 cvt + f16 MFMA)
    gemm_f32a<1><<<dim3(768), dim3(256), 0, stream>>>(key,   wkb, bk, Kb);
    gemm_f32a<0><<<dim3(768), dim3(256), 0, stream>>>(value, wvb, bv, Vb);

    // kv partials (+ fused column sums), then merged reduce -> km, vm, kvT
    kv_partial<<<dim3(NBH, 32), dim3(256), 0, stream>>>(Kb, Vb, sin_t, cos_t, pkv, pk, pv);
    kvred<<<dim3(NBH, 16), dim3(256), 0, stream>>>(pkv, pk, pv, kvT, km, vm);

    // Q projection with fused exact-z + rope
    gemm_q<<<dim3(768), dim3(256), 0, stream>>>(query, wqb, bq, km, sin_t, cos_t, Qr, zbuf);

    // res (in-place on Qr)
    res_mfma<<<dim3(NBH, N_SEQ / 128), dim3(256), 0, stream>>>(Qr, kvT, vm, zbuf);

    // output projection (fp32 out)
    gemm_f16a<<<dim3(768), dim3(256), 0, stream>>>(Qr, wob, bo, out);
}